// Round 6
// baseline (661.690 us; speedup 1.0000x reference)
//
#include <hip/hip_runtime.h>
#include <hip/hip_cooperative_groups.h>
#include <math.h>

namespace cg = cooperative_groups;

#define NV 8192
#define NE 4096
#define DIN 512
#define DH 256
#define CAP_E 96
#define CAP_V 64
#define NBLK 256
#define NTHR 512
#define NWAVE 8

// ---------------- workspace layout (float offsets) ----------------
#define OFF_XH   0                       // V*DH
#define OFF_Z    (OFF_XH + NV*DH)        // V*DH
#define OFF_Y    (OFF_Z  + NV*DH)        // E*DH
#define OFF_NCNT (OFF_Y  + NE*DH)        // V ints
#define OFF_ECNT (OFF_NCNT + NV)         // E*16 ints (line-padded counters)
#define OFF_EL   (OFF_ECNT + NE*16)      // E*CAP_E ints
#define OFF_NL   (OFF_EL + NE*CAP_E)     // V*CAP_V ints

using bf16x8 = __attribute__((ext_vector_type(8))) short;
using f32x4  = __attribute__((ext_vector_type(4))) float;

__device__ inline unsigned short f2bf(float f) {   // round-to-nearest-even
    union { float f; unsigned u; } v; v.f = f;
    unsigned r = v.u + 0x7FFF + ((v.u >> 16) & 1);
    return (unsigned short)(r >> 16);
}

struct Params {
    const float *X, *H, *Wp, *W0, *W1, *g0, *b0, *g1, *b1, *Wc, *bc;
    float *out, *Xh, *Z, *Y;
    int *ncnt, *ecnt, *elist, *nlist;
};

union SMem {
    struct { short As[2048]; short Bs[16384]; float redS[32][4]; float redQ[32][4]; } g;
    struct { int lcnt; int lbuf[CAP_V]; } s;
    struct { int lv[NWAVE][CAP_E]; float lc[NWAVE][CAP_E]; } e;
};

// ---------------- GEMM phase: C[NV,256] = A[NV,K] @ B[256,K]^T ----------------
// BM=32, BN=256, BK=64; 512 thr = 8 waves; wave (msub,wc) -> rows msub*16..+16,
// cols wc*64..+64. LN variant fuses relu+residual+LayerNorm (C doubles as Xh).
template<bool LN>
__device__ void gemm_phase(SMem& sm, const float* __restrict__ A,
                           const float* __restrict__ B,
                           float* __restrict__ C,
                           const float* __restrict__ g,
                           const float* __restrict__ b,
                           int K, int bid) {
    const int tid  = threadIdx.x;
    const int lane = tid & 63;
    const int w    = tid >> 6;          // 0..7
    const int msub = w >> 2, wc = w & 3;
    const int swz  = lane ^ ((lane >> 3) & 6);
    for (int t = bid; t < NV / 32; t += NBLK) {
        const int bm = t * 32;
        float4 ar, br[8];
        ar = *(const float4*)(A + (size_t)(bm + (tid >> 4)) * K + ((tid & 15) << 2));
#pragma unroll
        for (int it = 0; it < 8; ++it) {
            int i = tid + it * NTHR;
            br[it] = *(const float4*)(B + (size_t)(i >> 4) * K + ((i & 15) << 2));
        }
        f32x4 acc[4];
#pragma unroll
        for (int ni = 0; ni < 4; ++ni) acc[ni] = (f32x4){0.f, 0.f, 0.f, 0.f};

        for (int k0 = 0; k0 < K; k0 += 64) {
            __syncthreads();
            {   // A tile: 32x64, one float4 per thread
                int i = tid;
                int row = i >> 4, kk = (i & 15) << 2;
                int kc = kk >> 5, quad = (kk >> 3) & 3, j = kk & 7;
                int ln = (row & 15) + (quad << 4);
                int pp = ln ^ ((ln >> 3) & 6);
                ushort4 u = {f2bf(ar.x), f2bf(ar.y), f2bf(ar.z), f2bf(ar.w)};
                *(ushort4*)&sm.g.As[((row >> 4) * 2 + kc) * 512 + pp * 8 + j] = u;
            }
#pragma unroll
            for (int it = 0; it < 8; ++it) {
                int i = tid + it * NTHR;
                int row = i >> 4, kk = (i & 15) << 2;
                int kc = kk >> 5, quad = (kk >> 3) & 3, j = kk & 7;
                int ln = (row & 15) + (quad << 4);
                int pp = ln ^ ((ln >> 3) & 6);
                float4 v = br[it];
                ushort4 u = {f2bf(v.x), f2bf(v.y), f2bf(v.z), f2bf(v.w)};
                *(ushort4*)&sm.g.Bs[((row >> 4) * 2 + kc) * 512 + pp * 8 + j] = u;
            }
            __syncthreads();
            if (k0 + 64 < K) {
                int kn = k0 + 64;
                ar = *(const float4*)(A + (size_t)(bm + (tid >> 4)) * K + kn + ((tid & 15) << 2));
#pragma unroll
                for (int it = 0; it < 8; ++it) {
                    int i = tid + it * NTHR;
                    br[it] = *(const float4*)(B + (size_t)(i >> 4) * K + kn + ((i & 15) << 2));
                }
            }
#pragma unroll
            for (int kc = 0; kc < 2; ++kc) {
                bf16x8 af = *(const bf16x8*)&sm.g.As[(msub * 2 + kc) * 512 + swz * 8];
                bf16x8 bfr[4];
#pragma unroll
                for (int ni = 0; ni < 4; ++ni)
                    bfr[ni] = *(const bf16x8*)&sm.g.Bs[((wc * 4 + ni) * 2 + kc) * 512 + swz * 8];
#pragma unroll
                for (int ni = 0; ni < 4; ++ni)
                    acc[ni] = __builtin_amdgcn_mfma_f32_16x16x32_bf16(af, bfr[ni], acc[ni], 0, 0, 0);
            }
        }
        const int quad = lane >> 4, cl = lane & 15;
        if (!LN) {
#pragma unroll
            for (int ni = 0; ni < 4; ++ni)
#pragma unroll
                for (int r = 0; r < 4; ++r)
                    C[(size_t)(bm + msub * 16 + quad * 4 + r) * DH + wc * 64 + ni * 16 + cl]
                        = acc[ni][r];
        } else {
#pragma unroll
            for (int r = 0; r < 4; ++r) {
                int Rg = msub * 16 + quad * 4 + r;
                float s = 0.f, q = 0.f;
#pragma unroll
                for (int ni = 0; ni < 4; ++ni) {
                    int col = wc * 64 + ni * 16 + cl;
                    float v = fmaxf(acc[ni][r], 0.f) + C[(size_t)(bm + Rg) * DH + col];
                    acc[ni][r] = v;
                    s += v; q = fmaf(v, v, q);
                }
#pragma unroll
                for (int o = 1; o < 16; o <<= 1) {
                    s += __shfl_xor(s, o, 64);
                    q += __shfl_xor(q, o, 64);
                }
                if (cl == 0) { sm.g.redS[Rg][wc] = s; sm.g.redQ[Rg][wc] = q; }
            }
            __syncthreads();
#pragma unroll
            for (int r = 0; r < 4; ++r) {
                int Rg = msub * 16 + quad * 4 + r;
                float s = sm.g.redS[Rg][0] + sm.g.redS[Rg][1] + sm.g.redS[Rg][2] + sm.g.redS[Rg][3];
                float q = sm.g.redQ[Rg][0] + sm.g.redQ[Rg][1] + sm.g.redQ[Rg][2] + sm.g.redQ[Rg][3];
                float m = s * (1.0f / DH);
                float var = q * (1.0f / DH) - m * m;
                float rstd = rsqrtf(var + 1e-5f);
#pragma unroll
                for (int ni = 0; ni < 4; ++ni) {
                    int col = wc * 64 + ni * 16 + cl;
                    float v = (acc[ni][r] - m) * rstd * g[col] + b[col];
                    C[(size_t)(bm + Rg) * DH + col] = v;
                }
            }
        }
    }
}

// ---------------- scan phase: dense H -> adjacency lists + degrees ----------------
__device__ void scan_phase(SMem& sm, const Params& p, int bid) {
    const int t = threadIdx.x;   // 0..511, 8 floats each
    for (int v = bid; v < NV; v += NBLK) {
        __syncthreads();
        if (t == 0) sm.s.lcnt = 0;
        __syncthreads();
        const float4* H4 = (const float4*)(p.H + (size_t)v * NE);
        float4 h0 = H4[t * 2 + 0], h1 = H4[t * 2 + 1];
        float hv[8] = {h0.x, h0.y, h0.z, h0.w, h1.x, h1.y, h1.z, h1.w};
        int myE[8]; int n = 0;
        int e0 = t * 8;
#pragma unroll
        for (int j = 0; j < 8; ++j)
            if (hv[j] != 0.0f) myE[n++] = e0 + j;
        if (n > 0) {
            int s = atomicAdd(&sm.s.lcnt, n);
            for (int k = 0; k < n; ++k) {
                int ee = myE[k];
                if (s + k < CAP_V) sm.s.lbuf[s + k] = ee;
                int gc = atomicAdd(&p.ecnt[ee << 4], 1);
                if (gc < CAP_E) p.elist[ee * CAP_E + gc] = v;
            }
        }
        __syncthreads();
        int c = sm.s.lcnt;
        if (t == 0) p.ncnt[v] = c;
        int cc = min(c, CAP_V);
        for (int i = t; i < cc; i += NTHR) p.nlist[v * CAP_V + i] = sm.s.lbuf[i];
    }
}

// ---------------- weighted row-gather core (per-wave, float4 lanes) ----------------
__device__ __forceinline__ float4 gather_rows(const float4* __restrict__ src,
                                              const int* lv, const float* lcp,
                                              int cnt, int lane) {
    float4 a[8];
#pragma unroll
    for (int u = 0; u < 8; ++u) a[u] = (float4){0.f, 0.f, 0.f, 0.f};
    int i = 0;
    for (; i + 8 <= cnt; i += 8) {
#pragma unroll
        for (int u = 0; u < 8; ++u) {
            float4 x = src[lv[i + u] + lane]; float c = lcp[i + u];
            a[u].x = fmaf(c, x.x, a[u].x); a[u].y = fmaf(c, x.y, a[u].y);
            a[u].z = fmaf(c, x.z, a[u].z); a[u].w = fmaf(c, x.w, a[u].w);
        }
    }
    for (; i < cnt; ++i) {
        float4 x = src[lv[i] + lane]; float c = lcp[i];
        a[0].x = fmaf(c, x.x, a[0].x); a[0].y = fmaf(c, x.y, a[0].y);
        a[0].z = fmaf(c, x.z, a[0].z); a[0].w = fmaf(c, x.w, a[0].w);
    }
#pragma unroll
    for (int u = 4; u > 0; u >>= 1)
#pragma unroll
        for (int q = 0; q < u; ++q) {
            a[q].x += a[q + u].x; a[q].y += a[q + u].y;
            a[q].z += a[q + u].z; a[q].w += a[q + u].w;
        }
    return a[0];
}

// ---- Y[e,:] = rsqrt(de) * sum_{v in e} rsqrt(dv) * Xh[v,:] ----
__device__ void edge_phase(SMem& sm, const Params& p, int bid) {
    const int lane = threadIdx.x & 63, w = threadIdx.x >> 6;
    const float4* X4 = (const float4*)p.Xh;
    for (int e = bid * NWAVE + w; e < NE; e += NBLK * NWAVE) {
        int tc = p.ecnt[e << 4];
        int cnt = min(tc, CAP_E);
        for (int j = lane; j < cnt; j += 64) {
            int v = p.elist[e * CAP_E + j];
            sm.e.lv[w][j] = v * (DH / 4);
            sm.e.lc[w][j] = rsqrtf((float)p.ncnt[v]);
        }
        __syncthreads();
        float4 acc = gather_rows(X4, sm.e.lv[w], sm.e.lc[w], cnt, lane);
        float de = tc > 0 ? rsqrtf((float)tc) : 0.f;
        float4 o = {de * acc.x, de * acc.y, de * acc.z, de * acc.w};
        ((float4*)p.Y)[e * (DH / 4) + lane] = o;
    }
}

// ---- Z[v,:] = rsqrt(dv) * sum_{e ∋ v} rsqrt(de) * Y[e,:] ----
__device__ void node_phase(SMem& sm, const Params& p, int bid) {
    const int lane = threadIdx.x & 63, w = threadIdx.x >> 6;
    const float4* Y4 = (const float4*)p.Y;
    for (int v = bid * NWAVE + w; v < NV; v += NBLK * NWAVE) {
        int tc = p.ncnt[v];
        int cnt = min(tc, CAP_V);
        for (int j = lane; j < cnt; j += 64) {
            int e = p.nlist[v * CAP_V + j];
            sm.e.lv[w][j] = e * (DH / 4);
            sm.e.lc[w][j] = rsqrtf((float)p.ecnt[e << 4]);
        }
        __syncthreads();
        float4 acc = gather_rows(Y4, sm.e.lv[w], sm.e.lc[w], cnt, lane);
        float dv = tc > 0 ? rsqrtf((float)tc) : 0.f;
        float4 o = {dv * acc.x, dv * acc.y, dv * acc.z, dv * acc.w};
        ((float4*)p.Z)[v * (DH / 4) + lane] = o;
    }
}

// ---- mean-pool per edge + classifier + softmax ----
__device__ void pool_phase(SMem& sm, const Params& p, int bid) {
    const int lane = threadIdx.x & 63, w = threadIdx.x >> 6;
    const float4* X4 = (const float4*)p.Xh;
    const float4* W4 = (const float4*)p.Wc;
    for (int e = bid * NWAVE + w; e < NE; e += NBLK * NWAVE) {
        int tc = p.ecnt[e << 4];
        int cnt = min(tc, CAP_E);
        for (int j = lane; j < cnt; j += 64) {
            sm.e.lv[w][j] = p.elist[e * CAP_E + j] * (DH / 4);
            sm.e.lc[w][j] = 1.0f;
        }
        __syncthreads();
        float4 acc = gather_rows(X4, sm.e.lv[w], sm.e.lc[w], cnt, lane);
        float inv = tc > 0 ? 1.0f / (float)tc : 1.0f;
        float4 val = {acc.x * inv, acc.y * inv, acc.z * inv, acc.w * inv};
        float4 w0 = W4[lane], w1 = W4[64 + lane];
        float p0 = val.x * w0.x + val.y * w0.y + val.z * w0.z + val.w * w0.w;
        float p1 = val.x * w1.x + val.y * w1.y + val.z * w1.z + val.w * w1.w;
#pragma unroll
        for (int o = 32; o > 0; o >>= 1) {
            p0 += __shfl_down(p0, o, 64);
            p1 += __shfl_down(p1, o, 64);
        }
        if (lane == 0) {
            float l0 = p0 + p.bc[0], l1 = p1 + p.bc[1];
            float mx = fmaxf(l0, l1);
            float e0 = expf(l0 - mx), e1 = expf(l1 - mx);
            float s = 1.0f / (e0 + e1);
            p.out[e * 2 + 0] = e0 * s;
            p.out[e * 2 + 1] = e1 * s;
        }
    }
}

// ---------------- the megakernel (cooperative) ----------------
__global__ __launch_bounds__(NTHR, 2) void mega(Params p) {
    cg::grid_group grid = cg::this_grid();
    __shared__ SMem sm;
    const int bid = blockIdx.x;

    for (int i = bid * NTHR + threadIdx.x; i < NE * 16; i += NBLK * NTHR) p.ecnt[i] = 0;
    gemm_phase<false>(sm, p.X, p.Wp, p.Xh, nullptr, nullptr, DIN, bid);
    grid.sync();

    scan_phase(sm, p, bid);
    grid.sync();

    for (int l = 0; l < 2; ++l) {
        edge_phase(sm, p, bid);
        grid.sync();
        node_phase(sm, p, bid);
        grid.sync();
        gemm_phase<true>(sm, p.Z, l ? p.W1 : p.W0, p.Xh,
                         l ? p.g1 : p.g0, l ? p.b1 : p.b0, DH, bid);
        grid.sync();
    }

    pool_phase(sm, p, bid);
}

// ---------------- fallback: same phases as separate kernels ----------------
__global__ __launch_bounds__(NTHR, 2) void k_proj(Params p) {
    __shared__ SMem sm;
    gemm_phase<false>(sm, p.X, p.Wp, p.Xh, nullptr, nullptr, DIN, blockIdx.x);
}
__global__ __launch_bounds__(NTHR, 2) void k_scan(Params p) {
    __shared__ SMem sm;
    scan_phase(sm, p, blockIdx.x);
}
__global__ __launch_bounds__(NTHR, 2) void k_edge(Params p) {
    __shared__ SMem sm;
    edge_phase(sm, p, blockIdx.x);
}
__global__ __launch_bounds__(NTHR, 2) void k_node(Params p) {
    __shared__ SMem sm;
    node_phase(sm, p, blockIdx.x);
}
__global__ __launch_bounds__(NTHR, 2) void k_gemm_ln(Params p, const float* W,
                                                     const float* g, const float* b) {
    __shared__ SMem sm;
    gemm_phase<true>(sm, p.Z, W, p.Xh, g, b, DH, blockIdx.x);
}
__global__ __launch_bounds__(NTHR, 2) void k_pool(Params p) {
    __shared__ SMem sm;
    pool_phase(sm, p, blockIdx.x);
}

extern "C" void kernel_launch(void* const* d_in, const int* in_sizes, int n_in,
                              void* d_out, int out_size, void* d_ws, size_t ws_size,
                              hipStream_t stream) {
    float* ws = (float*)d_ws;
    Params p;
    p.X  = (const float*)d_in[0];
    p.H  = (const float*)d_in[1];
    p.Wp = (const float*)d_in[2];
    p.W0 = (const float*)d_in[3];
    p.W1 = (const float*)d_in[4];
    p.g0 = (const float*)d_in[5];
    p.b0 = (const float*)d_in[6];
    p.g1 = (const float*)d_in[7];
    p.b1 = (const float*)d_in[8];
    p.Wc = (const float*)d_in[9];
    p.bc = (const float*)d_in[10];
    p.out = (float*)d_out;
    p.Xh = ws + OFF_XH;
    p.Z  = ws + OFF_Z;
    p.Y  = ws + OFF_Y;
    p.ncnt  = (int*)(ws + OFF_NCNT);
    p.ecnt  = (int*)(ws + OFF_ECNT);
    p.elist = (int*)(ws + OFF_EL);
    p.nlist = (int*)(ws + OFF_NL);

    void* args[] = { &p };
    hipError_t err = hipLaunchCooperativeKernel(reinterpret_cast<const void*>(&mega),
                                                dim3(NBLK), dim3(NTHR), args, 0, stream);
    if (err != hipSuccess) {
        // fallback: identical phases, separate launches (deterministic every call)
        hipMemsetAsync(p.ecnt, 0, (size_t)(NE * 16) * sizeof(int), stream);
        k_proj<<<NBLK, NTHR, 0, stream>>>(p);
        k_scan<<<NBLK, NTHR, 0, stream>>>(p);
        for (int l = 0; l < 2; ++l) {
            k_edge<<<NBLK, NTHR, 0, stream>>>(p);
            k_node<<<NBLK, NTHR, 0, stream>>>(p);
            k_gemm_ln<<<NBLK, NTHR, 0, stream>>>(p, l ? p.W1 : p.W0,
                                                 l ? p.g1 : p.g0, l ? p.b1 : p.b0);
        }
        k_pool<<<NBLK, NTHR, 0, stream>>>(p);
    }
}

// Round 7
// 335.549 us; speedup vs baseline: 1.9720x; 1.9720x over previous
//
#include <hip/hip_runtime.h>
#include <math.h>

#define NV 8192
#define NE 4096
#define DIN 512
#define DH 256
#define CAP_E 96
#define CAP_V 64

// ---------------- workspace layout (float offsets) ----------------
#define OFF_XH   0                       // V*DH fp32
#define OFF_Z    (OFF_XH + NV*DH)        // V*DH fp32
#define OFF_Y    (OFF_Z  + NV*DH)        // E*DH fp32
#define OFF_NCNT (OFF_Y  + NE*DH)        // V ints
#define OFF_ECNT (OFF_NCNT + NV)         // E*16 ints (line-padded counters)
#define OFF_EL   (OFF_ECNT + NE*16)      // E*CAP_E ints
#define OFF_NL   (OFF_EL + NE*CAP_E)     // V*CAP_V ints
#define OFF_XHB  (OFF_NL + NV*CAP_V)     // V*DH bf16 (= V*DH/2 floats)

using bf16x8 = __attribute__((ext_vector_type(8))) short;
using f32x4  = __attribute__((ext_vector_type(4))) float;

__device__ inline unsigned short f2bf(float f) {   // round-to-nearest-even
    union { float f; unsigned u; } v; v.f = f;
    unsigned r = v.u + 0x7FFF + ((v.u >> 16) & 1);
    return (unsigned short)(r >> 16);
}
__device__ inline float b2f(unsigned short s) {
    union { unsigned u; float f; } v; v.u = ((unsigned)s) << 16; return v.f;
}

union ScanProjSmem {
    struct { short As[2048]; short Bs[16384]; } g;
    struct { int lcnt; int lbuf[CAP_V]; } s;
};

// ---- fused: blocks [0,256) do proj GEMM Xh = X @ Wp^T; blocks [256,8448) scan H ----
__global__ __launch_bounds__(256) void scan_proj(const float* __restrict__ H,
                                                 const float* __restrict__ X,
                                                 const float* __restrict__ Wp,
                                                 float* __restrict__ Xh,
                                                 unsigned short* __restrict__ Xhb,
                                                 int* __restrict__ edge_cnt,
                                                 int* __restrict__ node_cnt,
                                                 int* __restrict__ edge_list,
                                                 int* __restrict__ node_list) {
    __shared__ ScanProjSmem sm;
    const int tid = threadIdx.x;
    if (blockIdx.x >= NV / 32) {
        // ---------------- scan path: one block per node row ----------------
        int v = blockIdx.x - NV / 32;
        if (tid == 0) sm.s.lcnt = 0;
        __syncthreads();
        const float4* H4 = (const float4*)(H + (size_t)v * NE);
        float4 h0 = H4[tid * 4 + 0], h1 = H4[tid * 4 + 1];
        float4 h2 = H4[tid * 4 + 2], h3 = H4[tid * 4 + 3];
        float hv[16] = {h0.x, h0.y, h0.z, h0.w, h1.x, h1.y, h1.z, h1.w,
                        h2.x, h2.y, h2.z, h2.w, h3.x, h3.y, h3.z, h3.w};
        int myE[16]; int n = 0;
        int e0 = tid * 16;
#pragma unroll
        for (int j = 0; j < 16; ++j)
            if (hv[j] != 0.0f) myE[n++] = e0 + j;
        if (n > 0) {
            int s = atomicAdd(&sm.s.lcnt, n);
            for (int k = 0; k < n; ++k) {
                int ee = myE[k];
                if (s + k < CAP_V) sm.s.lbuf[s + k] = ee;
                int gc = atomicAdd(&edge_cnt[ee << 4], 1);
                if (gc < CAP_E) edge_list[ee * CAP_E + gc] = v;
            }
        }
        __syncthreads();
        int c = sm.s.lcnt;
        if (tid == 0) node_cnt[v] = c;
        int cc = min(c, CAP_V);
        for (int i = tid; i < cc; i += 256) node_list[v * CAP_V + i] = sm.s.lbuf[i];
        return;
    }
    // ---------------- proj GEMM path: BM=32, BN=256, BK=64, K=DIN ----------------
    const int K = DIN;
    const int lane = tid & 63;
    const int w    = tid >> 6;
    const int bm   = blockIdx.x * 32;
    const int swz  = lane ^ ((lane >> 3) & 6);
    float4 ar[2], br[16];
    {
        int i0 = tid, i1 = tid + 256;
        ar[0] = *(const float4*)(X + (size_t)(bm + (i0 >> 4)) * K + ((i0 & 15) << 2));
        ar[1] = *(const float4*)(X + (size_t)(bm + (i1 >> 4)) * K + ((i1 & 15) << 2));
#pragma unroll
        for (int it = 0; it < 16; ++it) {
            int i = tid + it * 256;
            br[it] = *(const float4*)(Wp + (size_t)(i >> 4) * K + ((i & 15) << 2));
        }
    }
    f32x4 acc[2][4];
#pragma unroll
    for (int mi = 0; mi < 2; ++mi)
#pragma unroll
        for (int ni = 0; ni < 4; ++ni) acc[mi][ni] = (f32x4){0.f, 0.f, 0.f, 0.f};
    for (int k0 = 0; k0 < K; k0 += 64) {
        __syncthreads();
#pragma unroll
        for (int s = 0; s < 2; ++s) {
            int i = tid + s * 256;
            int row = i >> 4, kk = (i & 15) << 2;
            int kc = kk >> 5, quad = (kk >> 3) & 3, j = kk & 7;
            int ln = (row & 15) + (quad << 4);
            int pp = ln ^ ((ln >> 3) & 6);
            float4 v = ar[s];
            ushort4 u = {f2bf(v.x), f2bf(v.y), f2bf(v.z), f2bf(v.w)};
            *(ushort4*)&sm.g.As[((row >> 4) * 2 + kc) * 512 + pp * 8 + j] = u;
        }
#pragma unroll
        for (int it = 0; it < 16; ++it) {
            int i = tid + it * 256;
            int row = i >> 4, kk = (i & 15) << 2;
            int kc = kk >> 5, quad = (kk >> 3) & 3, j = kk & 7;
            int ln = (row & 15) + (quad << 4);
            int pp = ln ^ ((ln >> 3) & 6);
            float4 v = br[it];
            ushort4 u = {f2bf(v.x), f2bf(v.y), f2bf(v.z), f2bf(v.w)};
            *(ushort4*)&sm.g.Bs[((row >> 4) * 2 + kc) * 512 + pp * 8 + j] = u;
        }
        __syncthreads();
        if (k0 + 64 < K) {
            int kn = k0 + 64;
            int i0 = tid, i1 = tid + 256;
            ar[0] = *(const float4*)(X + (size_t)(bm + (i0 >> 4)) * K + kn + ((i0 & 15) << 2));
            ar[1] = *(const float4*)(X + (size_t)(bm + (i1 >> 4)) * K + kn + ((i1 & 15) << 2));
#pragma unroll
            for (int it = 0; it < 16; ++it) {
                int i = tid + it * 256;
                br[it] = *(const float4*)(Wp + (size_t)(i >> 4) * K + kn + ((i & 15) << 2));
            }
        }
#pragma unroll
        for (int kc = 0; kc < 2; ++kc) {
            bf16x8 af[2], bfr[4];
            af[0] = *(const bf16x8*)&sm.g.As[(0 * 2 + kc) * 512 + swz * 8];
            af[1] = *(const bf16x8*)&sm.g.As[(1 * 2 + kc) * 512 + swz * 8];
#pragma unroll
            for (int ni = 0; ni < 4; ++ni)
                bfr[ni] = *(const bf16x8*)&sm.g.Bs[((w * 4 + ni) * 2 + kc) * 512 + swz * 8];
#pragma unroll
            for (int mi = 0; mi < 2; ++mi)
#pragma unroll
                for (int ni = 0; ni < 4; ++ni)
                    acc[mi][ni] = __builtin_amdgcn_mfma_f32_16x16x32_bf16(
                        af[mi], bfr[ni], acc[mi][ni], 0, 0, 0);
        }
    }
    const int quad = lane >> 4, cl = lane & 15;
#pragma unroll
    for (int mi = 0; mi < 2; ++mi)
#pragma unroll
        for (int ni = 0; ni < 4; ++ni)
#pragma unroll
            for (int r = 0; r < 4; ++r) {
                float v = acc[mi][ni][r];
                size_t idx = (size_t)(bm + mi * 16 + quad * 4 + r) * DH + w * 64 + ni * 16 + cl;
                Xh[idx] = v;
                Xhb[idx] = f2bf(v);
            }
}

// ------- fused: Xh = LayerNorm(Xh + relu(Z @ W^T)) * g + b; also writes Xhb ----
__global__ __launch_bounds__(256) void gemm_relu_res_ln(const float* __restrict__ Z,
                                                        const float* __restrict__ W,
                                                        float* __restrict__ Xh,
                                                        unsigned short* __restrict__ Xhb,
                                                        const float* __restrict__ g,
                                                        const float* __restrict__ b) {
    const int K = DH;
    __shared__ short As[2048];
    __shared__ short Bs[16384];
    __shared__ float redS[32][4];
    __shared__ float redQ[32][4];
    const int tid  = threadIdx.x;
    const int lane = tid & 63;
    const int w    = tid >> 6;
    const int bm   = blockIdx.x * 32;
    const int swz  = lane ^ ((lane >> 3) & 6);

    float4 ar[2], br[16];
    {
        int i0 = tid, i1 = tid + 256;
        ar[0] = *(const float4*)(Z + (size_t)(bm + (i0 >> 4)) * K + ((i0 & 15) << 2));
        ar[1] = *(const float4*)(Z + (size_t)(bm + (i1 >> 4)) * K + ((i1 & 15) << 2));
#pragma unroll
        for (int it = 0; it < 16; ++it) {
            int i = tid + it * 256;
            br[it] = *(const float4*)(W + (size_t)(i >> 4) * K + ((i & 15) << 2));
        }
    }
    f32x4 acc[2][4];
#pragma unroll
    for (int mi = 0; mi < 2; ++mi)
#pragma unroll
        for (int ni = 0; ni < 4; ++ni) acc[mi][ni] = (f32x4){0.f, 0.f, 0.f, 0.f};

    for (int k0 = 0; k0 < K; k0 += 64) {
        __syncthreads();
#pragma unroll
        for (int s = 0; s < 2; ++s) {
            int i = tid + s * 256;
            int row = i >> 4, kk = (i & 15) << 2;
            int kc = kk >> 5, quad = (kk >> 3) & 3, j = kk & 7;
            int ln = (row & 15) + (quad << 4);
            int pp = ln ^ ((ln >> 3) & 6);
            float4 v = ar[s];
            ushort4 u = {f2bf(v.x), f2bf(v.y), f2bf(v.z), f2bf(v.w)};
            *(ushort4*)&As[((row >> 4) * 2 + kc) * 512 + pp * 8 + j] = u;
        }
#pragma unroll
        for (int it = 0; it < 16; ++it) {
            int i = tid + it * 256;
            int row = i >> 4, kk = (i & 15) << 2;
            int kc = kk >> 5, quad = (kk >> 3) & 3, j = kk & 7;
            int ln = (row & 15) + (quad << 4);
            int pp = ln ^ ((ln >> 3) & 6);
            float4 v = br[it];
            ushort4 u = {f2bf(v.x), f2bf(v.y), f2bf(v.z), f2bf(v.w)};
            *(ushort4*)&Bs[((row >> 4) * 2 + kc) * 512 + pp * 8 + j] = u;
        }
        __syncthreads();
        if (k0 + 64 < K) {
            int kn = k0 + 64;
            int i0 = tid, i1 = tid + 256;
            ar[0] = *(const float4*)(Z + (size_t)(bm + (i0 >> 4)) * K + kn + ((i0 & 15) << 2));
            ar[1] = *(const float4*)(Z + (size_t)(bm + (i1 >> 4)) * K + kn + ((i1 & 15) << 2));
#pragma unroll
            for (int it = 0; it < 16; ++it) {
                int i = tid + it * 256;
                br[it] = *(const float4*)(W + (size_t)(i >> 4) * K + kn + ((i & 15) << 2));
            }
        }
#pragma unroll
        for (int kc = 0; kc < 2; ++kc) {
            bf16x8 af[2], bfr[4];
            af[0] = *(const bf16x8*)&As[(0 * 2 + kc) * 512 + swz * 8];
            af[1] = *(const bf16x8*)&As[(1 * 2 + kc) * 512 + swz * 8];
#pragma unroll
            for (int ni = 0; ni < 4; ++ni)
                bfr[ni] = *(const bf16x8*)&Bs[((w * 4 + ni) * 2 + kc) * 512 + swz * 8];
#pragma unroll
            for (int mi = 0; mi < 2; ++mi)
#pragma unroll
                for (int ni = 0; ni < 4; ++ni)
                    acc[mi][ni] = __builtin_amdgcn_mfma_f32_16x16x32_bf16(
                        af[mi], bfr[ni], acc[mi][ni], 0, 0, 0);
        }
    }
    const int quad = lane >> 4, cl = lane & 15;
#pragma unroll
    for (int mi = 0; mi < 2; ++mi)
#pragma unroll
        for (int r = 0; r < 4; ++r) {
            int row = bm + mi * 16 + quad * 4 + r;
            float s = 0.f, q = 0.f;
#pragma unroll
            for (int ni = 0; ni < 4; ++ni) {
                int col = w * 64 + ni * 16 + cl;
                float v = fmaxf(acc[mi][ni][r], 0.f) + Xh[(size_t)row * DH + col];
                acc[mi][ni][r] = v;
                s += v; q = fmaf(v, v, q);
            }
#pragma unroll
            for (int o = 1; o < 16; o <<= 1) {
                s += __shfl_xor(s, o, 64);
                q += __shfl_xor(q, o, 64);
            }
            if (cl == 0) {
                redS[mi * 16 + quad * 4 + r][w] = s;
                redQ[mi * 16 + quad * 4 + r][w] = q;
            }
        }
    __syncthreads();
#pragma unroll
    for (int mi = 0; mi < 2; ++mi)
#pragma unroll
        for (int r = 0; r < 4; ++r) {
            int R = mi * 16 + quad * 4 + r;
            float s = redS[R][0] + redS[R][1] + redS[R][2] + redS[R][3];
            float q = redQ[R][0] + redQ[R][1] + redQ[R][2] + redQ[R][3];
            float m = s * (1.0f / DH);
            float var = q * (1.0f / DH) - m * m;
            float rstd = rsqrtf(var + 1e-5f);
            int row = bm + R;
#pragma unroll
            for (int ni = 0; ni < 4; ++ni) {
                int col = w * 64 + ni * 16 + cl;
                float v = (acc[mi][ni][r] - m) * rstd * g[col] + b[col];
                size_t idx = (size_t)row * DH + col;
                Xh[idx] = v;
                Xhb[idx] = f2bf(v);
            }
        }
}

// ---- Y[e,:] = rsqrt(de) * sum_{v in e} rsqrt(dv) * Xhb[v,:]  (bf16 src, 64 thr) ----
__global__ __launch_bounds__(64) void edge_gather(const unsigned short* __restrict__ Xhb,
                                                  const int* __restrict__ edge_cnt,
                                                  const int* __restrict__ edge_list,
                                                  const int* __restrict__ node_cnt,
                                                  float* __restrict__ Y) {
    int e = blockIdx.x;
    int tid = threadIdx.x;
    __shared__ int   lv[CAP_E];
    __shared__ float lc[CAP_E];
    int tc = edge_cnt[e << 4];
    int cnt = min(tc, CAP_E);
    for (int j = tid; j < cnt; j += 64) {
        int v = edge_list[e * CAP_E + j];
        lv[j] = v * (DH / 4);           // row stride in ushort4 units
        lc[j] = rsqrtf((float)node_cnt[v]);
    }
    __syncthreads();
    const ushort4* X4 = (const ushort4*)Xhb;
    float4 a[8];
#pragma unroll
    for (int u = 0; u < 8; ++u) a[u] = (float4){0.f, 0.f, 0.f, 0.f};
    int i = 0;
    for (; i + 8 <= cnt; i += 8) {
#pragma unroll
        for (int u = 0; u < 8; ++u) {
            ushort4 h = X4[lv[i + u] + tid]; float c = lc[i + u];
            a[u].x = fmaf(c, b2f(h.x), a[u].x); a[u].y = fmaf(c, b2f(h.y), a[u].y);
            a[u].z = fmaf(c, b2f(h.z), a[u].z); a[u].w = fmaf(c, b2f(h.w), a[u].w);
        }
    }
    for (; i < cnt; ++i) {
        ushort4 h = X4[lv[i] + tid]; float c = lc[i];
        a[0].x = fmaf(c, b2f(h.x), a[0].x); a[0].y = fmaf(c, b2f(h.y), a[0].y);
        a[0].z = fmaf(c, b2f(h.z), a[0].z); a[0].w = fmaf(c, b2f(h.w), a[0].w);
    }
#pragma unroll
    for (int u = 4; u > 0; u >>= 1)
#pragma unroll
        for (int q = 0; q < u; ++q) {
            a[q].x += a[q + u].x; a[q].y += a[q + u].y;
            a[q].z += a[q + u].z; a[q].w += a[q + u].w;
        }
    float de = tc > 0 ? rsqrtf((float)tc) : 0.f;
    float4 o = {de * a[0].x, de * a[0].y, de * a[0].z, de * a[0].w};
    ((float4*)Y)[e * (DH / 4) + tid] = o;
}

// ---- Z[v,:] = rsqrt(dv) * sum_{e ∋ v} rsqrt(de) * Y[e,:]  (fp32 src, 64 thr) ----
__global__ __launch_bounds__(64) void node_gather(const float* __restrict__ Y,
                                                  const int* __restrict__ node_cnt,
                                                  const int* __restrict__ node_list,
                                                  const int* __restrict__ edge_cnt,
                                                  float* __restrict__ Z) {
    int v = blockIdx.x;
    int tid = threadIdx.x;
    __shared__ int   le[CAP_V];
    __shared__ float lc[CAP_V];
    int tc = node_cnt[v];
    int cnt = min(tc, CAP_V);
    if (tid < cnt) {
        int e = node_list[v * CAP_V + tid];
        le[tid] = e * (DH / 4);
        lc[tid] = rsqrtf((float)edge_cnt[e << 4]);
    }
    __syncthreads();
    const float4* Y4 = (const float4*)Y;
    float4 a[8];
#pragma unroll
    for (int u = 0; u < 8; ++u) a[u] = (float4){0.f, 0.f, 0.f, 0.f};
    int i = 0;
    for (; i + 8 <= cnt; i += 8) {
#pragma unroll
        for (int u = 0; u < 8; ++u) {
            float4 x = Y4[le[i + u] + tid]; float c = lc[i + u];
            a[u].x = fmaf(c, x.x, a[u].x); a[u].y = fmaf(c, x.y, a[u].y);
            a[u].z = fmaf(c, x.z, a[u].z); a[u].w = fmaf(c, x.w, a[u].w);
        }
    }
    for (; i < cnt; ++i) {
        float4 x = Y4[le[i] + tid]; float c = lc[i];
        a[0].x = fmaf(c, x.x, a[0].x); a[0].y = fmaf(c, x.y, a[0].y);
        a[0].z = fmaf(c, x.z, a[0].z); a[0].w = fmaf(c, x.w, a[0].w);
    }
#pragma unroll
    for (int u = 4; u > 0; u >>= 1)
#pragma unroll
        for (int q = 0; q < u; ++q) {
            a[q].x += a[q + u].x; a[q].y += a[q + u].y;
            a[q].z += a[q + u].z; a[q].w += a[q + u].w;
        }
    float dv = tc > 0 ? rsqrtf((float)tc) : 0.f;
    float4 o = {dv * a[0].x, dv * a[0].y, dv * a[0].z, dv * a[0].w};
    ((float4*)Z)[v * (DH / 4) + tid] = o;
}

// ---------------- fused mean-pool + classifier + softmax (64 thr, fp32 src) ----------------
__global__ __launch_bounds__(64) void pool_classify(const float* __restrict__ Xh,
                                                    const int* __restrict__ edge_cnt,
                                                    const int* __restrict__ edge_list,
                                                    const float* __restrict__ Wc,
                                                    const float* __restrict__ bc,
                                                    float* __restrict__ out) {
    int e = blockIdx.x;
    int tid = threadIdx.x;
    __shared__ int lv[CAP_E];
    int tc = edge_cnt[e << 4];
    int cnt = min(tc, CAP_E);
    for (int j = tid; j < cnt; j += 64) lv[j] = edge_list[e * CAP_E + j] * (DH / 4);
    __syncthreads();
    const float4* X4 = (const float4*)Xh;
    float4 a[8];
#pragma unroll
    for (int u = 0; u < 8; ++u) a[u] = (float4){0, 0, 0, 0};
    int i = 0;
    for (; i + 8 <= cnt; i += 8) {
#pragma unroll
        for (int u = 0; u < 8; ++u) {
            float4 x = X4[lv[i + u] + tid];
            a[u].x += x.x; a[u].y += x.y; a[u].z += x.z; a[u].w += x.w;
        }
    }
    for (; i < cnt; ++i) {
        float4 x = X4[lv[i] + tid];
        a[0].x += x.x; a[0].y += x.y; a[0].z += x.z; a[0].w += x.w;
    }
#pragma unroll
    for (int u = 4; u > 0; u >>= 1)
#pragma unroll
        for (int q = 0; q < u; ++q) {
            a[q].x += a[q + u].x; a[q].y += a[q + u].y;
            a[q].z += a[q + u].z; a[q].w += a[q + u].w;
        }
    float inv = tc > 0 ? 1.0f / (float)tc : 1.0f;
    float4 val = {a[0].x * inv, a[0].y * inv, a[0].z * inv, a[0].w * inv};
    const float4* W4 = (const float4*)Wc;
    float4 w0 = W4[tid], w1 = W4[64 + tid];
    float p0 = val.x * w0.x + val.y * w0.y + val.z * w0.z + val.w * w0.w;
    float p1 = val.x * w1.x + val.y * w1.y + val.z * w1.z + val.w * w1.w;
#pragma unroll
    for (int o = 32; o > 0; o >>= 1) {
        p0 += __shfl_down(p0, o, 64);
        p1 += __shfl_down(p1, o, 64);
    }
    if (tid == 0) {
        float l0 = p0 + bc[0], l1 = p1 + bc[1];
        float mx = fmaxf(l0, l1);
        float e0 = expf(l0 - mx), e1 = expf(l1 - mx);
        float s = 1.0f / (e0 + e1);
        out[e * 2 + 0] = e0 * s;
        out[e * 2 + 1] = e1 * s;
    }
}

extern "C" void kernel_launch(void* const* d_in, const int* in_sizes, int n_in,
                              void* d_out, int out_size, void* d_ws, size_t ws_size,
                              hipStream_t stream) {
    const float* X  = (const float*)d_in[0];
    const float* H  = (const float*)d_in[1];
    const float* Wp = (const float*)d_in[2];
    const float* W0 = (const float*)d_in[3];
    const float* W1 = (const float*)d_in[4];
    const float* g0 = (const float*)d_in[5];
    const float* b0 = (const float*)d_in[6];
    const float* g1 = (const float*)d_in[7];
    const float* b1 = (const float*)d_in[8];
    const float* Wc = (const float*)d_in[9];
    const float* bc = (const float*)d_in[10];
    float* out = (float*)d_out;

    float* ws = (float*)d_ws;
    float* Xh  = ws + OFF_XH;
    float* Z   = ws + OFF_Z;
    float* Y   = ws + OFF_Y;
    int* node_cnt  = (int*)(ws + OFF_NCNT);
    int* edge_cnt  = (int*)(ws + OFF_ECNT);
    int* edge_list = (int*)(ws + OFF_EL);
    int* node_list = (int*)(ws + OFF_NL);
    unsigned short* Xhb = (unsigned short*)(ws + OFF_XHB);

    hipMemsetAsync(edge_cnt, 0, (size_t)(NE * 16) * sizeof(int), stream);

    // fused: proj GEMM (blocks 0..255) + H scan (blocks 256..8447)
    scan_proj<<<NV / 32 + NV, 256, 0, stream>>>(H, X, Wp, Xh, Xhb,
                                                edge_cnt, node_cnt, edge_list, node_list);

    const float* Ws[2] = {W0, W1};
    const float* gs[2] = {g0, g1};
    const float* bs[2] = {b0, b1};
    for (int l = 0; l < 2; ++l) {
        edge_gather<<<NE, 64, 0, stream>>>(Xhb, edge_cnt, edge_list, node_cnt, Y);
        node_gather<<<NV, 64, 0, stream>>>(Y, node_cnt, node_list, edge_cnt, Z);
        gemm_relu_res_ln<<<NV / 32, 256, 0, stream>>>(Z, Ws[l], Xh, Xhb, gs[l], bs[l]);
    }

    pool_classify<<<NE, 64, 0, stream>>>(Xh, edge_cnt, edge_list, Wc, bc, out);
}

// Round 8
// 327.883 us; speedup vs baseline: 2.0181x; 1.0234x over previous
//
#include <hip/hip_runtime.h>
#include <math.h>

#define NV 8192
#define NE 4096
#define DIN 512
#define DH 256
#define CAP_E 96
#define CAP_V 64
#define NPROJ (NV / 32)      // 256 proj-GEMM blocks
#define NSCAN (NV / 4)       // 2048 scan blocks (4 rows/block, wave-per-row)

// ---------------- workspace layout (float offsets) ----------------
#define OFF_XH   0                       // V*DH fp32
#define OFF_Z    (OFF_XH + NV*DH)        // V*DH fp32
#define OFF_Y    (OFF_Z  + NV*DH)        // E*DH fp32
#define OFF_NCNT (OFF_Y  + NE*DH)        // V ints
#define OFF_ECNT (OFF_NCNT + NV)         // E*16 ints (line-padded counters)
#define OFF_EL   (OFF_ECNT + NE*16)      // E*CAP_E ints
#define OFF_NL   (OFF_EL + NE*CAP_E)     // V*CAP_V ints
#define OFF_XHB  (OFF_NL + NV*CAP_V)     // V*DH bf16 (= V*DH/2 floats)

using bf16x8 = __attribute__((ext_vector_type(8))) short;
using f32x4  = __attribute__((ext_vector_type(4))) float;

__device__ inline unsigned short f2bf(float f) {   // round-to-nearest-even
    union { float f; unsigned u; } v; v.f = f;
    unsigned r = v.u + 0x7FFF + ((v.u >> 16) & 1);
    return (unsigned short)(r >> 16);
}
__device__ inline float b2f(unsigned short s) {
    union { unsigned u; float f; } v; v.u = ((unsigned)s) << 16; return v.f;
}

union ScanProjSmem {
    struct { short As[1024]; short Bs[8192]; } g;        // BK=32: 2+16 KB
    struct { int lcnt[4]; int lbuf[4][CAP_V]; } s;       // ~1 KB
};

// ---- fused: blocks [0,NPROJ) proj GEMM Xh = X @ Wp^T (BK=32);
//      blocks [NPROJ, NPROJ+NSCAN): scan H, wave-per-row, 16-deep MLP ----
__global__ __launch_bounds__(256) void scan_proj(const float* __restrict__ H,
                                                 const float* __restrict__ X,
                                                 const float* __restrict__ Wp,
                                                 float* __restrict__ Xh,
                                                 unsigned short* __restrict__ Xhb,
                                                 int* __restrict__ edge_cnt,
                                                 int* __restrict__ node_cnt,
                                                 int* __restrict__ edge_list,
                                                 int* __restrict__ node_list) {
    __shared__ ScanProjSmem sm;
    const int tid = threadIdx.x;
    if (blockIdx.x >= NPROJ) {
        // ---------------- scan path: one WAVE per node row ----------------
        const int w = tid >> 6, lane = tid & 63;
        const int v = (blockIdx.x - NPROJ) * 4 + w;
        if (lane == 0) sm.s.lcnt[w] = 0;
        const float4* H4 = (const float4*)(H + (size_t)v * NE);
        float4 h[16];
#pragma unroll
        for (int it = 0; it < 16; ++it) h[it] = H4[lane + 64 * it];   // 16 indep loads
#pragma unroll
        for (int it = 0; it < 16; ++it) {
            float hv[4] = {h[it].x, h[it].y, h[it].z, h[it].w};
#pragma unroll
            for (int c = 0; c < 4; ++c) {
                if (hv[c] != 0.0f) {
                    int ee = 256 * it + 4 * lane + c;
                    int s = atomicAdd(&sm.s.lcnt[w], 1);
                    if (s < CAP_V) sm.s.lbuf[w][s] = ee;
                    int gc = atomicAdd(&edge_cnt[ee << 4], 1);
                    if (gc < CAP_E) edge_list[ee * CAP_E + gc] = v;
                }
            }
        }
        int c = sm.s.lcnt[w];          // wave-synchronous: all lanes' LDS atomics done
        if (lane == 0) node_cnt[v] = c;
        int cc = min(c, CAP_V);
        for (int i = lane; i < cc; i += 64) node_list[v * CAP_V + i] = sm.s.lbuf[w][i];
        return;
    }
    // ---------------- proj GEMM path: BM=32, BN=256, BK=32, K=DIN ----------------
    const int K = DIN;
    const int lane = tid & 63;
    const int w    = tid >> 6;
    const int bm   = blockIdx.x * 32;
    const int swz  = lane ^ ((lane >> 3) & 6);
    float4 ar, br[8];
    ar = *(const float4*)(X + (size_t)(bm + (tid >> 3)) * K + ((tid & 7) << 2));
#pragma unroll
    for (int it = 0; it < 8; ++it) {
        int i = tid + it * 256;
        br[it] = *(const float4*)(Wp + (size_t)(i >> 3) * K + ((i & 7) << 2));
    }
    f32x4 acc[2][4];
#pragma unroll
    for (int mi = 0; mi < 2; ++mi)
#pragma unroll
        for (int ni = 0; ni < 4; ++ni) acc[mi][ni] = (f32x4){0.f, 0.f, 0.f, 0.f};
    for (int k0 = 0; k0 < K; k0 += 32) {
        __syncthreads();
        {   // stage A: 32x32, one float4/thread
            int row = tid >> 3, kk = (tid & 7) << 2;
            int quad = kk >> 3, j = kk & 7;
            int ln = (row & 15) + (quad << 4);
            int pp = ln ^ ((ln >> 3) & 6);
            ushort4 u = {f2bf(ar.x), f2bf(ar.y), f2bf(ar.z), f2bf(ar.w)};
            *(ushort4*)&sm.g.As[(row >> 4) * 512 + pp * 8 + j] = u;
        }
#pragma unroll
        for (int it = 0; it < 8; ++it) {   // stage B: 256x32
            int i = tid + it * 256;
            int row = i >> 3, kk = (i & 7) << 2;
            int quad = kk >> 3, j = kk & 7;
            int ln = (row & 15) + (quad << 4);
            int pp = ln ^ ((ln >> 3) & 6);
            float4 v = br[it];
            ushort4 u = {f2bf(v.x), f2bf(v.y), f2bf(v.z), f2bf(v.w)};
            *(ushort4*)&sm.g.Bs[(row >> 4) * 512 + pp * 8 + j] = u;
        }
        __syncthreads();
        if (k0 + 32 < K) {
            int kn = k0 + 32;
            ar = *(const float4*)(X + (size_t)(bm + (tid >> 3)) * K + kn + ((tid & 7) << 2));
#pragma unroll
            for (int it = 0; it < 8; ++it) {
                int i = tid + it * 256;
                br[it] = *(const float4*)(Wp + (size_t)(i >> 3) * K + kn + ((i & 7) << 2));
            }
        }
        bf16x8 af[2], bfr[4];
        af[0] = *(const bf16x8*)&sm.g.As[0 * 512 + swz * 8];
        af[1] = *(const bf16x8*)&sm.g.As[1 * 512 + swz * 8];
#pragma unroll
        for (int ni = 0; ni < 4; ++ni)
            bfr[ni] = *(const bf16x8*)&sm.g.Bs[(w * 4 + ni) * 512 + swz * 8];
#pragma unroll
        for (int mi = 0; mi < 2; ++mi)
#pragma unroll
            for (int ni = 0; ni < 4; ++ni)
                acc[mi][ni] = __builtin_amdgcn_mfma_f32_16x16x32_bf16(
                    af[mi], bfr[ni], acc[mi][ni], 0, 0, 0);
    }
    const int quad = lane >> 4, cl = lane & 15;
#pragma unroll
    for (int mi = 0; mi < 2; ++mi)
#pragma unroll
        for (int ni = 0; ni < 4; ++ni)
#pragma unroll
            for (int r = 0; r < 4; ++r) {
                float v = acc[mi][ni][r];
                size_t idx = (size_t)(bm + mi * 16 + quad * 4 + r) * DH + w * 64 + ni * 16 + cl;
                Xh[idx] = v;
                Xhb[idx] = f2bf(v);
            }
}

// ------- fused: Xh = LayerNorm(Xh + relu(Z @ W^T)) * g + b; also writes Xhb ----
__global__ __launch_bounds__(256) void gemm_relu_res_ln(const float* __restrict__ Z,
                                                        const float* __restrict__ W,
                                                        float* __restrict__ Xh,
                                                        unsigned short* __restrict__ Xhb,
                                                        const float* __restrict__ g,
                                                        const float* __restrict__ b) {
    const int K = DH;
    __shared__ short As[2048];
    __shared__ short Bs[16384];
    __shared__ float redS[32][4];
    __shared__ float redQ[32][4];
    const int tid  = threadIdx.x;
    const int lane = tid & 63;
    const int w    = tid >> 6;
    const int bm   = blockIdx.x * 32;
    const int swz  = lane ^ ((lane >> 3) & 6);

    float4 ar[2], br[16];
    {
        int i0 = tid, i1 = tid + 256;
        ar[0] = *(const float4*)(Z + (size_t)(bm + (i0 >> 4)) * K + ((i0 & 15) << 2));
        ar[1] = *(const float4*)(Z + (size_t)(bm + (i1 >> 4)) * K + ((i1 & 15) << 2));
#pragma unroll
        for (int it = 0; it < 16; ++it) {
            int i = tid + it * 256;
            br[it] = *(const float4*)(W + (size_t)(i >> 4) * K + ((i & 15) << 2));
        }
    }
    f32x4 acc[2][4];
#pragma unroll
    for (int mi = 0; mi < 2; ++mi)
#pragma unroll
        for (int ni = 0; ni < 4; ++ni) acc[mi][ni] = (f32x4){0.f, 0.f, 0.f, 0.f};

    for (int k0 = 0; k0 < K; k0 += 64) {
        __syncthreads();
#pragma unroll
        for (int s = 0; s < 2; ++s) {
            int i = tid + s * 256;
            int row = i >> 4, kk = (i & 15) << 2;
            int kc = kk >> 5, quad = (kk >> 3) & 3, j = kk & 7;
            int ln = (row & 15) + (quad << 4);
            int pp = ln ^ ((ln >> 3) & 6);
            float4 v = ar[s];
            ushort4 u = {f2bf(v.x), f2bf(v.y), f2bf(v.z), f2bf(v.w)};
            *(ushort4*)&As[((row >> 4) * 2 + kc) * 512 + pp * 8 + j] = u;
        }
#pragma unroll
        for (int it = 0; it < 16; ++it) {
            int i = tid + it * 256;
            int row = i >> 4, kk = (i & 15) << 2;
            int kc = kk >> 5, quad = (kk >> 3) & 3, j = kk & 7;
            int ln = (row & 15) + (quad << 4);
            int pp = ln ^ ((ln >> 3) & 6);
            float4 v = br[it];
            ushort4 u = {f2bf(v.x), f2bf(v.y), f2bf(v.z), f2bf(v.w)};
            *(ushort4*)&Bs[((row >> 4) * 2 + kc) * 512 + pp * 8 + j] = u;
        }
        __syncthreads();
        if (k0 + 64 < K) {
            int kn = k0 + 64;
            int i0 = tid, i1 = tid + 256;
            ar[0] = *(const float4*)(Z + (size_t)(bm + (i0 >> 4)) * K + kn + ((i0 & 15) << 2));
            ar[1] = *(const float4*)(Z + (size_t)(bm + (i1 >> 4)) * K + kn + ((i1 & 15) << 2));
#pragma unroll
            for (int it = 0; it < 16; ++it) {
                int i = tid + it * 256;
                br[it] = *(const float4*)(W + (size_t)(i >> 4) * K + kn + ((i & 15) << 2));
            }
        }
#pragma unroll
        for (int kc = 0; kc < 2; ++kc) {
            bf16x8 af[2], bfr[4];
            af[0] = *(const bf16x8*)&As[(0 * 2 + kc) * 512 + swz * 8];
            af[1] = *(const bf16x8*)&As[(1 * 2 + kc) * 512 + swz * 8];
#pragma unroll
            for (int ni = 0; ni < 4; ++ni)
                bfr[ni] = *(const bf16x8*)&Bs[((w * 4 + ni) * 2 + kc) * 512 + swz * 8];
#pragma unroll
            for (int mi = 0; mi < 2; ++mi)
#pragma unroll
                for (int ni = 0; ni < 4; ++ni)
                    acc[mi][ni] = __builtin_amdgcn_mfma_f32_16x16x32_bf16(
                        af[mi], bfr[ni], acc[mi][ni], 0, 0, 0);
        }
    }
    const int quad = lane >> 4, cl = lane & 15;
#pragma unroll
    for (int mi = 0; mi < 2; ++mi)
#pragma unroll
        for (int r = 0; r < 4; ++r) {
            int row = bm + mi * 16 + quad * 4 + r;
            float s = 0.f, q = 0.f;
#pragma unroll
            for (int ni = 0; ni < 4; ++ni) {
                int col = w * 64 + ni * 16 + cl;
                float v = fmaxf(acc[mi][ni][r], 0.f) + Xh[(size_t)row * DH + col];
                acc[mi][ni][r] = v;
                s += v; q = fmaf(v, v, q);
            }
#pragma unroll
            for (int o = 1; o < 16; o <<= 1) {
                s += __shfl_xor(s, o, 64);
                q += __shfl_xor(q, o, 64);
            }
            if (cl == 0) {
                redS[mi * 16 + quad * 4 + r][w] = s;
                redQ[mi * 16 + quad * 4 + r][w] = q;
            }
        }
    __syncthreads();
#pragma unroll
    for (int mi = 0; mi < 2; ++mi)
#pragma unroll
        for (int r = 0; r < 4; ++r) {
            int R = mi * 16 + quad * 4 + r;
            float s = redS[R][0] + redS[R][1] + redS[R][2] + redS[R][3];
            float q = redQ[R][0] + redQ[R][1] + redQ[R][2] + redQ[R][3];
            float m = s * (1.0f / DH);
            float var = q * (1.0f / DH) - m * m;
            float rstd = rsqrtf(var + 1e-5f);
            int row = bm + R;
#pragma unroll
            for (int ni = 0; ni < 4; ++ni) {
                int col = w * 64 + ni * 16 + cl;
                float v = (acc[mi][ni][r] - m) * rstd * g[col] + b[col];
                size_t idx = (size_t)row * DH + col;
                Xh[idx] = v;
                Xhb[idx] = f2bf(v);
            }
        }
}

// ---- Y[e,:] = rsqrt(de) * sum_{v in e} rsqrt(dv) * Xhb[v,:]  (bf16 src, 64 thr) ----
__global__ __launch_bounds__(64) void edge_gather(const unsigned short* __restrict__ Xhb,
                                                  const int* __restrict__ edge_cnt,
                                                  const int* __restrict__ edge_list,
                                                  const int* __restrict__ node_cnt,
                                                  float* __restrict__ Y) {
    int e = blockIdx.x;
    int tid = threadIdx.x;
    __shared__ int   lv[CAP_E];
    __shared__ float lc[CAP_E];
    int tc = edge_cnt[e << 4];
    int cnt = min(tc, CAP_E);
    for (int j = tid; j < cnt; j += 64) {
        int v = edge_list[e * CAP_E + j];
        lv[j] = v * (DH / 4);
        lc[j] = rsqrtf((float)node_cnt[v]);
    }
    __syncthreads();
    const ushort4* X4 = (const ushort4*)Xhb;
    float4 a[8];
#pragma unroll
    for (int u = 0; u < 8; ++u) a[u] = (float4){0.f, 0.f, 0.f, 0.f};
    int i = 0;
    for (; i + 8 <= cnt; i += 8) {
#pragma unroll
        for (int u = 0; u < 8; ++u) {
            ushort4 h = X4[lv[i + u] + tid]; float c = lc[i + u];
            a[u].x = fmaf(c, b2f(h.x), a[u].x); a[u].y = fmaf(c, b2f(h.y), a[u].y);
            a[u].z = fmaf(c, b2f(h.z), a[u].z); a[u].w = fmaf(c, b2f(h.w), a[u].w);
        }
    }
    for (; i < cnt; ++i) {
        ushort4 h = X4[lv[i] + tid]; float c = lc[i];
        a[0].x = fmaf(c, b2f(h.x), a[0].x); a[0].y = fmaf(c, b2f(h.y), a[0].y);
        a[0].z = fmaf(c, b2f(h.z), a[0].z); a[0].w = fmaf(c, b2f(h.w), a[0].w);
    }
#pragma unroll
    for (int u = 4; u > 0; u >>= 1)
#pragma unroll
        for (int q = 0; q < u; ++q) {
            a[q].x += a[q + u].x; a[q].y += a[q + u].y;
            a[q].z += a[q + u].z; a[q].w += a[q + u].w;
        }
    float de = tc > 0 ? rsqrtf((float)tc) : 0.f;
    float4 o = {de * a[0].x, de * a[0].y, de * a[0].z, de * a[0].w};
    ((float4*)Y)[e * (DH / 4) + tid] = o;
}

// ---- Z[v,:] = rsqrt(dv) * sum_{e ∋ v} rsqrt(de) * Y[e,:]  (fp32 src, 64 thr) ----
__global__ __launch_bounds__(64) void node_gather(const float* __restrict__ Y,
                                                  const int* __restrict__ node_cnt,
                                                  const int* __restrict__ node_list,
                                                  const int* __restrict__ edge_cnt,
                                                  float* __restrict__ Z) {
    int v = blockIdx.x;
    int tid = threadIdx.x;
    __shared__ int   le[CAP_V];
    __shared__ float lc[CAP_V];
    int tc = node_cnt[v];
    int cnt = min(tc, CAP_V);
    if (tid < cnt) {
        int e = node_list[v * CAP_V + tid];
        le[tid] = e * (DH / 4);
        lc[tid] = rsqrtf((float)edge_cnt[e << 4]);
    }
    __syncthreads();
    const float4* Y4 = (const float4*)Y;
    float4 a[8];
#pragma unroll
    for (int u = 0; u < 8; ++u) a[u] = (float4){0.f, 0.f, 0.f, 0.f};
    int i = 0;
    for (; i + 8 <= cnt; i += 8) {
#pragma unroll
        for (int u = 0; u < 8; ++u) {
            float4 x = Y4[le[i + u] + tid]; float c = lc[i + u];
            a[u].x = fmaf(c, x.x, a[u].x); a[u].y = fmaf(c, x.y, a[u].y);
            a[u].z = fmaf(c, x.z, a[u].z); a[u].w = fmaf(c, x.w, a[u].w);
        }
    }
    for (; i < cnt; ++i) {
        float4 x = Y4[le[i] + tid]; float c = lc[i];
        a[0].x = fmaf(c, x.x, a[0].x); a[0].y = fmaf(c, x.y, a[0].y);
        a[0].z = fmaf(c, x.z, a[0].z); a[0].w = fmaf(c, x.w, a[0].w);
    }
#pragma unroll
    for (int u = 4; u > 0; u >>= 1)
#pragma unroll
        for (int q = 0; q < u; ++q) {
            a[q].x += a[q + u].x; a[q].y += a[q + u].y;
            a[q].z += a[q + u].z; a[q].w += a[q + u].w;
        }
    float dv = tc > 0 ? rsqrtf((float)tc) : 0.f;
    float4 o = {dv * a[0].x, dv * a[0].y, dv * a[0].z, dv * a[0].w};
    ((float4*)Z)[v * (DH / 4) + tid] = o;
}

// ---------------- fused mean-pool + classifier + softmax (64 thr, fp32 src) ----------------
__global__ __launch_bounds__(64) void pool_classify(const float* __restrict__ Xh,
                                                    const int* __restrict__ edge_cnt,
                                                    const int* __restrict__ edge_list,
                                                    const float* __restrict__ Wc,
                                                    const float* __restrict__ bc,
                                                    float* __restrict__ out) {
    int e = blockIdx.x;
    int tid = threadIdx.x;
    __shared__ int lv[CAP_E];
    int tc = edge_cnt[e << 4];
    int cnt = min(tc, CAP_E);
    for (int j = tid; j < cnt; j += 64) lv[j] = edge_list[e * CAP_E + j] * (DH / 4);
    __syncthreads();
    const float4* X4 = (const float4*)Xh;
    float4 a[8];
#pragma unroll
    for (int u = 0; u < 8; ++u) a[u] = (float4){0, 0, 0, 0};
    int i = 0;
    for (; i + 8 <= cnt; i += 8) {
#pragma unroll
        for (int u = 0; u < 8; ++u) {
            float4 x = X4[lv[i + u] + tid];
            a[u].x += x.x; a[u].y += x.y; a[u].z += x.z; a[u].w += x.w;
        }
    }
    for (; i < cnt; ++i) {
        float4 x = X4[lv[i] + tid];
        a[0].x += x.x; a[0].y += x.y; a[0].z += x.z; a[0].w += x.w;
    }
#pragma unroll
    for (int u = 4; u > 0; u >>= 1)
#pragma unroll
        for (int q = 0; q < u; ++q) {
            a[q].x += a[q + u].x; a[q].y += a[q + u].y;
            a[q].z += a[q + u].z; a[q].w += a[q + u].w;
        }
    float inv = tc > 0 ? 1.0f / (float)tc : 1.0f;
    float4 val = {a[0].x * inv, a[0].y * inv, a[0].z * inv, a[0].w * inv};
    const float4* W4 = (const float4*)Wc;
    float4 w0 = W4[tid], w1 = W4[64 + tid];
    float p0 = val.x * w0.x + val.y * w0.y + val.z * w0.z + val.w * w0.w;
    float p1 = val.x * w1.x + val.y * w1.y + val.z * w1.z + val.w * w1.w;
#pragma unroll
    for (int o = 32; o > 0; o >>= 1) {
        p0 += __shfl_down(p0, o, 64);
        p1 += __shfl_down(p1, o, 64);
    }
    if (tid == 0) {
        float l0 = p0 + bc[0], l1 = p1 + bc[1];
        float mx = fmaxf(l0, l1);
        float e0 = expf(l0 - mx), e1 = expf(l1 - mx);
        float s = 1.0f / (e0 + e1);
        out[e * 2 + 0] = e0 * s;
        out[e * 2 + 1] = e1 * s;
    }
}

extern "C" void kernel_launch(void* const* d_in, const int* in_sizes, int n_in,
                              void* d_out, int out_size, void* d_ws, size_t ws_size,
                              hipStream_t stream) {
    const float* X  = (const float*)d_in[0];
    const float* H  = (const float*)d_in[1];
    const float* Wp = (const float*)d_in[2];
    const float* W0 = (const float*)d_in[3];
    const float* W1 = (const float*)d_in[4];
    const float* g0 = (const float*)d_in[5];
    const float* b0 = (const float*)d_in[6];
    const float* g1 = (const float*)d_in[7];
    const float* b1 = (const float*)d_in[8];
    const float* Wc = (const float*)d_in[9];
    const float* bc = (const float*)d_in[10];
    float* out = (float*)d_out;

    float* ws = (float*)d_ws;
    float* Xh  = ws + OFF_XH;
    float* Z   = ws + OFF_Z;
    float* Y   = ws + OFF_Y;
    int* node_cnt  = (int*)(ws + OFF_NCNT);
    int* edge_cnt  = (int*)(ws + OFF_ECNT);
    int* edge_list = (int*)(ws + OFF_EL);
    int* node_list = (int*)(ws + OFF_NL);
    unsigned short* Xhb = (unsigned short*)(ws + OFF_XHB);

    hipMemsetAsync(edge_cnt, 0, (size_t)(NE * 16) * sizeof(int), stream);

    // fused: proj GEMM (blocks 0..255) + H scan (blocks 256..2303, wave-per-row)
    scan_proj<<<NPROJ + NSCAN, 256, 0, stream>>>(H, X, Wp, Xh, Xhb,
                                                 edge_cnt, node_cnt, edge_list, node_list);

    const float* Ws[2] = {W0, W1};
    const float* gs[2] = {g0, g1};
    const float* bs[2] = {b0, b1};
    for (int l = 0; l < 2; ++l) {
        edge_gather<<<NE, 64, 0, stream>>>(Xhb, edge_cnt, edge_list, node_cnt, Y);
        node_gather<<<NV, 64, 0, stream>>>(Y, node_cnt, node_list, edge_cnt, Z);
        gemm_relu_res_ln<<<NV / 32, 256, 0, stream>>>(Z, Ws[l], Xh, Xhb, gs[l], bs[l]);
    }

    pool_classify<<<NE, 64, 0, stream>>>(Xh, edge_cnt, edge_list, Wc, bc, out);
}

// Round 9
// 310.281 us; speedup vs baseline: 2.1326x; 1.0567x over previous
//
#include <hip/hip_runtime.h>
#include <math.h>

#define NV 8192
#define NE 4096
#define DIN 512
#define DH 256
#define CAP_E 96
#define CAP_V 64
#define NPROJ (NV / 32)      // 256 proj-GEMM blocks
#define NSCAN (NV / 4)       // 2048 scan blocks (4 rows/block, wave-per-row)

// ---------------- workspace layout (float offsets) ----------------
#define OFF_XH   0                       // V*DH fp32
#define OFF_Z    (OFF_XH + NV*DH)        // V*DH fp32
#define OFF_Y    (OFF_Z  + NV*DH)        // E*DH fp32
#define OFF_NCNT (OFF_Y  + NE*DH)        // V ints
#define OFF_ECNT (OFF_NCNT + NV)         // E*16 ints (line-padded counters)
#define OFF_EL   (OFF_ECNT + NE*16)      // E*CAP_E ints
#define OFF_NL   (OFF_EL + NE*CAP_E)     // V*CAP_V ints
#define OFF_XHB  (OFF_NL + NV*CAP_V)     // V*DH bf16 (= V*DH/2 floats)

using bf16x8 = __attribute__((ext_vector_type(8))) short;
using f32x4  = __attribute__((ext_vector_type(4))) float;

__device__ inline unsigned short f2bf(float f) {   // round-to-nearest-even
    union { float f; unsigned u; } v; v.f = f;
    unsigned r = v.u + 0x7FFF + ((v.u >> 16) & 1);
    return (unsigned short)(r >> 16);
}
__device__ inline float b2f(unsigned short s) {
    union { unsigned u; float f; } v; v.u = ((unsigned)s) << 16; return v.f;
}

// ---- fused: blocks [0,NPROJ) proj GEMM Xh = X @ Wp^T (BK=32);
//      blocks [NPROJ, NPROJ+NSCAN): scan H, wave-per-row, batched atomics ----
__global__ __launch_bounds__(256) void scan_proj(const float* __restrict__ H,
                                                 const float* __restrict__ X,
                                                 const float* __restrict__ Wp,
                                                 float* __restrict__ Xh,
                                                 unsigned short* __restrict__ Xhb,
                                                 int* __restrict__ edge_cnt,
                                                 int* __restrict__ node_cnt,
                                                 int* __restrict__ edge_list,
                                                 int* __restrict__ node_list) {
    __shared__ short AsBs[1024 + 8192];    // proj GEMM staging only (scan uses none)
    const int tid = threadIdx.x;
    if (blockIdx.x >= NPROJ) {
        // ---------------- scan path: one WAVE per node row, no LDS ----------------
        const int w = tid >> 6, lane = tid & 63;
        const int v = (blockIdx.x - NPROJ) * 4 + w;
        const float4* H4 = (const float4*)(H + (size_t)v * NE);
        float4 h[16];
#pragma unroll
        for (int it = 0; it < 16; ++it) h[it] = H4[lane + 64 * it];   // 16 indep 1KB loads
        // build per-lane 64-bit hit mask (bit j=it*4+c -> edge 256*it+4*lane+c)
        unsigned long long m = 0ull;
#pragma unroll
        for (int it = 0; it < 16; ++it) {
            float hv[4] = {h[it].x, h[it].y, h[it].z, h[it].w};
#pragma unroll
            for (int c = 0; c < 4; ++c)
                m |= (hv[c] != 0.0f ? 1ull : 0ull) << (it * 4 + c);
        }
        int n = __builtin_popcountll(m);
        // wave prefix-sum of n -> deterministic node_list placement (no atomics)
        int pre = n;
#pragma unroll
        for (int o = 1; o < 64; o <<= 1) {
            int t = __shfl_up(pre, o, 64);
            if (lane >= o) pre += t;
        }
        int total = __shfl(pre, 63, 64);
        int base = pre - n;
        if (lane == 0) node_cnt[v] = total;
        // extract up to 4 hits into registers
        int e_arr[4] = {0, 0, 0, 0};
        {
            unsigned long long mm = m;
#pragma unroll
            for (int u = 0; u < 4; ++u) {
                if (mm) {
                    int j = __builtin_ctzll(mm);
                    mm &= mm - 1;
                    e_arr[u] = 256 * (j >> 2) + 4 * lane + (j & 3);
                }
            }
        }
        // 4 independent predicated atomics (one latency window), then stores
        int s_arr[4];
#pragma unroll
        for (int u = 0; u < 4; ++u)
            s_arr[u] = (u < n) ? atomicAdd(&edge_cnt[e_arr[u] << 4], 1) : 0;
#pragma unroll
        for (int u = 0; u < 4; ++u) {
            if (u < n) {
                if (s_arr[u] < CAP_E) edge_list[e_arr[u] * CAP_E + s_arr[u]] = v;
                int idx = base + u;
                if (idx < CAP_V) node_list[v * CAP_V + idx] = e_arr[u];
            }
        }
        // rare overflow (n > 4)
        if (n > 4) {
            unsigned long long mm = m;
            mm &= mm - 1; mm &= mm - 1; mm &= mm - 1; mm &= mm - 1;
            int k = 4;
            while (mm) {
                int j = __builtin_ctzll(mm); mm &= mm - 1;
                int ee = 256 * (j >> 2) + 4 * lane + (j & 3);
                int gc = atomicAdd(&edge_cnt[ee << 4], 1);
                if (gc < CAP_E) edge_list[ee * CAP_E + gc] = v;
                int idx = base + k;
                if (idx < CAP_V) node_list[v * CAP_V + idx] = ee;
                ++k;
            }
        }
        return;
    }
    // ---------------- proj GEMM path: BM=32, BN=256, BK=32, K=DIN ----------------
    short* As = AsBs;
    short* Bs = AsBs + 1024;
    const int K = DIN;
    const int lane = tid & 63;
    const int w    = tid >> 6;
    const int bm   = blockIdx.x * 32;
    const int swz  = lane ^ ((lane >> 3) & 6);
    float4 ar, br[8];
    ar = *(const float4*)(X + (size_t)(bm + (tid >> 3)) * K + ((tid & 7) << 2));
#pragma unroll
    for (int it = 0; it < 8; ++it) {
        int i = tid + it * 256;
        br[it] = *(const float4*)(Wp + (size_t)(i >> 3) * K + ((i & 7) << 2));
    }
    f32x4 acc[2][4];
#pragma unroll
    for (int mi = 0; mi < 2; ++mi)
#pragma unroll
        for (int ni = 0; ni < 4; ++ni) acc[mi][ni] = (f32x4){0.f, 0.f, 0.f, 0.f};
    for (int k0 = 0; k0 < K; k0 += 32) {
        __syncthreads();
        {   // stage A: 32x32, one float4/thread
            int row = tid >> 3, kk = (tid & 7) << 2;
            int quad = kk >> 3, j = kk & 7;
            int ln = (row & 15) + (quad << 4);
            int pp = ln ^ ((ln >> 3) & 6);
            ushort4 u = {f2bf(ar.x), f2bf(ar.y), f2bf(ar.z), f2bf(ar.w)};
            *(ushort4*)&As[(row >> 4) * 512 + pp * 8 + j] = u;
        }
#pragma unroll
        for (int it = 0; it < 8; ++it) {   // stage B: 256x32
            int i = tid + it * 256;
            int row = i >> 3, kk = (i & 7) << 2;
            int quad = kk >> 3, j = kk & 7;
            int ln = (row & 15) + (quad << 4);
            int pp = ln ^ ((ln >> 3) & 6);
            float4 v = br[it];
            ushort4 u = {f2bf(v.x), f2bf(v.y), f2bf(v.z), f2bf(v.w)};
            *(ushort4*)&Bs[(row >> 4) * 512 + pp * 8 + j] = u;
        }
        __syncthreads();
        if (k0 + 32 < K) {
            int kn = k0 + 32;
            ar = *(const float4*)(X + (size_t)(bm + (tid >> 3)) * K + kn + ((tid & 7) << 2));
#pragma unroll
            for (int it = 0; it < 8; ++it) {
                int i = tid + it * 256;
                br[it] = *(const float4*)(Wp + (size_t)(i >> 3) * K + kn + ((i & 7) << 2));
            }
        }
        bf16x8 af[2], bfr[4];
        af[0] = *(const bf16x8*)&As[0 * 512 + swz * 8];
        af[1] = *(const bf16x8*)&As[1 * 512 + swz * 8];
#pragma unroll
        for (int ni = 0; ni < 4; ++ni)
            bfr[ni] = *(const bf16x8*)&Bs[(w * 4 + ni) * 512 + swz * 8];
#pragma unroll
        for (int mi = 0; mi < 2; ++mi)
#pragma unroll
            for (int ni = 0; ni < 4; ++ni)
                acc[mi][ni] = __builtin_amdgcn_mfma_f32_16x16x32_bf16(
                    af[mi], bfr[ni], acc[mi][ni], 0, 0, 0);
    }
    const int quad = lane >> 4, cl = lane & 15;
#pragma unroll
    for (int mi = 0; mi < 2; ++mi)
#pragma unroll
        for (int ni = 0; ni < 4; ++ni)
#pragma unroll
            for (int r = 0; r < 4; ++r) {
                float v = acc[mi][ni][r];
                size_t idx = (size_t)(bm + mi * 16 + quad * 4 + r) * DH + w * 64 + ni * 16 + cl;
                Xh[idx] = v;
                Xhb[idx] = f2bf(v);
            }
}

// ------- fused: Xh = LayerNorm(Xh + relu(Z @ W^T)) * g + b; also writes Xhb ----
__global__ __launch_bounds__(256) void gemm_relu_res_ln(const float* __restrict__ Z,
                                                        const float* __restrict__ W,
                                                        float* __restrict__ Xh,
                                                        unsigned short* __restrict__ Xhb,
                                                        const float* __restrict__ g,
                                                        const float* __restrict__ b) {
    const int K = DH;
    __shared__ short As[2048];
    __shared__ short Bs[16384];
    __shared__ float redS[32][4];
    __shared__ float redQ[32][4];
    const int tid  = threadIdx.x;
    const int lane = tid & 63;
    const int w    = tid >> 6;
    const int bm   = blockIdx.x * 32;
    const int swz  = lane ^ ((lane >> 3) & 6);

    float4 ar[2], br[16];
    {
        int i0 = tid, i1 = tid + 256;
        ar[0] = *(const float4*)(Z + (size_t)(bm + (i0 >> 4)) * K + ((i0 & 15) << 2));
        ar[1] = *(const float4*)(Z + (size_t)(bm + (i1 >> 4)) * K + ((i1 & 15) << 2));
#pragma unroll
        for (int it = 0; it < 16; ++it) {
            int i = tid + it * 256;
            br[it] = *(const float4*)(W + (size_t)(i >> 4) * K + ((i & 15) << 2));
        }
    }
    f32x4 acc[2][4];
#pragma unroll
    for (int mi = 0; mi < 2; ++mi)
#pragma unroll
        for (int ni = 0; ni < 4; ++ni) acc[mi][ni] = (f32x4){0.f, 0.f, 0.f, 0.f};

    for (int k0 = 0; k0 < K; k0 += 64) {
        __syncthreads();
#pragma unroll
        for (int s = 0; s < 2; ++s) {
            int i = tid + s * 256;
            int row = i >> 4, kk = (i & 15) << 2;
            int kc = kk >> 5, quad = (kk >> 3) & 3, j = kk & 7;
            int ln = (row & 15) + (quad << 4);
            int pp = ln ^ ((ln >> 3) & 6);
            float4 v = ar[s];
            ushort4 u = {f2bf(v.x), f2bf(v.y), f2bf(v.z), f2bf(v.w)};
            *(ushort4*)&As[((row >> 4) * 2 + kc) * 512 + pp * 8 + j] = u;
        }
#pragma unroll
        for (int it = 0; it < 16; ++it) {
            int i = tid + it * 256;
            int row = i >> 4, kk = (i & 15) << 2;
            int kc = kk >> 5, quad = (kk >> 3) & 3, j = kk & 7;
            int ln = (row & 15) + (quad << 4);
            int pp = ln ^ ((ln >> 3) & 6);
            float4 v = br[it];
            ushort4 u = {f2bf(v.x), f2bf(v.y), f2bf(v.z), f2bf(v.w)};
            *(ushort4*)&Bs[((row >> 4) * 2 + kc) * 512 + pp * 8 + j] = u;
        }
        __syncthreads();
        if (k0 + 64 < K) {
            int kn = k0 + 64;
            int i0 = tid, i1 = tid + 256;
            ar[0] = *(const float4*)(Z + (size_t)(bm + (i0 >> 4)) * K + kn + ((i0 & 15) << 2));
            ar[1] = *(const float4*)(Z + (size_t)(bm + (i1 >> 4)) * K + kn + ((i1 & 15) << 2));
#pragma unroll
            for (int it = 0; it < 16; ++it) {
                int i = tid + it * 256;
                br[it] = *(const float4*)(W + (size_t)(i >> 4) * K + kn + ((i & 15) << 2));
            }
        }
#pragma unroll
        for (int kc = 0; kc < 2; ++kc) {
            bf16x8 af[2], bfr[4];
            af[0] = *(const bf16x8*)&As[(0 * 2 + kc) * 512 + swz * 8];
            af[1] = *(const bf16x8*)&As[(1 * 2 + kc) * 512 + swz * 8];
#pragma unroll
            for (int ni = 0; ni < 4; ++ni)
                bfr[ni] = *(const bf16x8*)&Bs[((w * 4 + ni) * 2 + kc) * 512 + swz * 8];
#pragma unroll
            for (int mi = 0; mi < 2; ++mi)
#pragma unroll
                for (int ni = 0; ni < 4; ++ni)
                    acc[mi][ni] = __builtin_amdgcn_mfma_f32_16x16x32_bf16(
                        af[mi], bfr[ni], acc[mi][ni], 0, 0, 0);
        }
    }
    const int quad = lane >> 4, cl = lane & 15;
#pragma unroll
    for (int mi = 0; mi < 2; ++mi)
#pragma unroll
        for (int r = 0; r < 4; ++r) {
            int row = bm + mi * 16 + quad * 4 + r;
            float s = 0.f, q = 0.f;
#pragma unroll
            for (int ni = 0; ni < 4; ++ni) {
                int col = w * 64 + ni * 16 + cl;
                float v = fmaxf(acc[mi][ni][r], 0.f) + Xh[(size_t)row * DH + col];
                acc[mi][ni][r] = v;
                s += v; q = fmaf(v, v, q);
            }
#pragma unroll
            for (int o = 1; o < 16; o <<= 1) {
                s += __shfl_xor(s, o, 64);
                q += __shfl_xor(q, o, 64);
            }
            if (cl == 0) {
                redS[mi * 16 + quad * 4 + r][w] = s;
                redQ[mi * 16 + quad * 4 + r][w] = q;
            }
        }
    __syncthreads();
#pragma unroll
    for (int mi = 0; mi < 2; ++mi)
#pragma unroll
        for (int r = 0; r < 4; ++r) {
            int R = mi * 16 + quad * 4 + r;
            float s = redS[R][0] + redS[R][1] + redS[R][2] + redS[R][3];
            float q = redQ[R][0] + redQ[R][1] + redQ[R][2] + redQ[R][3];
            float m = s * (1.0f / DH);
            float var = q * (1.0f / DH) - m * m;
            float rstd = rsqrtf(var + 1e-5f);
            int row = bm + R;
#pragma unroll
            for (int ni = 0; ni < 4; ++ni) {
                int col = w * 64 + ni * 16 + cl;
                float v = (acc[mi][ni][r] - m) * rstd * g[col] + b[col];
                size_t idx = (size_t)row * DH + col;
                Xh[idx] = v;
                Xhb[idx] = f2bf(v);
            }
        }
}

// ---- Y[e,:] = rsqrt(de) * sum_{v in e} rsqrt(dv) * Xhb[v,:]  (bf16 src, 64 thr) ----
__global__ __launch_bounds__(64) void edge_gather(const unsigned short* __restrict__ Xhb,
                                                  const int* __restrict__ edge_cnt,
                                                  const int* __restrict__ edge_list,
                                                  const int* __restrict__ node_cnt,
                                                  float* __restrict__ Y) {
    int e = blockIdx.x;
    int tid = threadIdx.x;
    __shared__ int   lv[CAP_E];
    __shared__ float lc[CAP_E];
    int tc = edge_cnt[e << 4];
    int cnt = min(tc, CAP_E);
    for (int j = tid; j < cnt; j += 64) {
        int v = edge_list[e * CAP_E + j];
        lv[j] = v * (DH / 4);
        lc[j] = rsqrtf((float)node_cnt[v]);
    }
    __syncthreads();
    const ushort4* X4 = (const ushort4*)Xhb;
    float4 a[8];
#pragma unroll
    for (int u = 0; u < 8; ++u) a[u] = (float4){0.f, 0.f, 0.f, 0.f};
    int i = 0;
    for (; i + 8 <= cnt; i += 8) {
#pragma unroll
        for (int u = 0; u < 8; ++u) {
            ushort4 h = X4[lv[i + u] + tid]; float c = lc[i + u];
            a[u].x = fmaf(c, b2f(h.x), a[u].x); a[u].y = fmaf(c, b2f(h.y), a[u].y);
            a[u].z = fmaf(c, b2f(h.z), a[u].z); a[u].w = fmaf(c, b2f(h.w), a[u].w);
        }
    }
    for (; i < cnt; ++i) {
        ushort4 h = X4[lv[i] + tid]; float c = lc[i];
        a[0].x = fmaf(c, b2f(h.x), a[0].x); a[0].y = fmaf(c, b2f(h.y), a[0].y);
        a[0].z = fmaf(c, b2f(h.z), a[0].z); a[0].w = fmaf(c, b2f(h.w), a[0].w);
    }
#pragma unroll
    for (int u = 4; u > 0; u >>= 1)
#pragma unroll
        for (int q = 0; q < u; ++q) {
            a[q].x += a[q + u].x; a[q].y += a[q + u].y;
            a[q].z += a[q + u].z; a[q].w += a[q + u].w;
        }
    float de = tc > 0 ? rsqrtf((float)tc) : 0.f;
    float4 o = {de * a[0].x, de * a[0].y, de * a[0].z, de * a[0].w};
    ((float4*)Y)[e * (DH / 4) + tid] = o;
}

// ---- Z[v,:] = rsqrt(dv) * sum_{e ∋ v} rsqrt(de) * Y[e,:]  (fp32 src, 64 thr) ----
__global__ __launch_bounds__(64) void node_gather(const float* __restrict__ Y,
                                                  const int* __restrict__ node_cnt,
                                                  const int* __restrict__ node_list,
                                                  const int* __restrict__ edge_cnt,
                                                  float* __restrict__ Z) {
    int v = blockIdx.x;
    int tid = threadIdx.x;
    __shared__ int   le[CAP_V];
    __shared__ float lc[CAP_V];
    int tc = node_cnt[v];
    int cnt = min(tc, CAP_V);
    if (tid < cnt) {
        int e = node_list[v * CAP_V + tid];
        le[tid] = e * (DH / 4);
        lc[tid] = rsqrtf((float)edge_cnt[e << 4]);
    }
    __syncthreads();
    const float4* Y4 = (const float4*)Y;
    float4 a[8];
#pragma unroll
    for (int u = 0; u < 8; ++u) a[u] = (float4){0.f, 0.f, 0.f, 0.f};
    int i = 0;
    for (; i + 8 <= cnt; i += 8) {
#pragma unroll
        for (int u = 0; u < 8; ++u) {
            float4 x = Y4[le[i + u] + tid]; float c = lc[i + u];
            a[u].x = fmaf(c, x.x, a[u].x); a[u].y = fmaf(c, x.y, a[u].y);
            a[u].z = fmaf(c, x.z, a[u].z); a[u].w = fmaf(c, x.w, a[u].w);
        }
    }
    for (; i < cnt; ++i) {
        float4 x = Y4[le[i] + tid]; float c = lc[i];
        a[0].x = fmaf(c, x.x, a[0].x); a[0].y = fmaf(c, x.y, a[0].y);
        a[0].z = fmaf(c, x.z, a[0].z); a[0].w = fmaf(c, x.w, a[0].w);
    }
#pragma unroll
    for (int u = 4; u > 0; u >>= 1)
#pragma unroll
        for (int q = 0; q < u; ++q) {
            a[q].x += a[q + u].x; a[q].y += a[q + u].y;
            a[q].z += a[q + u].z; a[q].w += a[q + u].w;
        }
    float dv = tc > 0 ? rsqrtf((float)tc) : 0.f;
    float4 o = {dv * a[0].x, dv * a[0].y, dv * a[0].z, dv * a[0].w};
    ((float4*)Z)[v * (DH / 4) + tid] = o;
}

// ---------------- fused mean-pool + classifier + softmax (64 thr, fp32 src) ----------------
__global__ __launch_bounds__(64) void pool_classify(const float* __restrict__ Xh,
                                                    const int* __restrict__ edge_cnt,
                                                    const int* __restrict__ edge_list,
                                                    const float* __restrict__ Wc,
                                                    const float* __restrict__ bc,
                                                    float* __restrict__ out) {
    int e = blockIdx.x;
    int tid = threadIdx.x;
    __shared__ int lv[CAP_E];
    int tc = edge_cnt[e << 4];
    int cnt = min(tc, CAP_E);
    for (int j = tid; j < cnt; j += 64) lv[j] = edge_list[e * CAP_E + j] * (DH / 4);
    __syncthreads();
    const float4* X4 = (const float4*)Xh;
    float4 a[8];
#pragma unroll
    for (int u = 0; u < 8; ++u) a[u] = (float4){0, 0, 0, 0};
    int i = 0;
    for (; i + 8 <= cnt; i += 8) {
#pragma unroll
        for (int u = 0; u < 8; ++u) {
            float4 x = X4[lv[i + u] + tid];
            a[u].x += x.x; a[u].y += x.y; a[u].z += x.z; a[u].w += x.w;
        }
    }
    for (; i < cnt; ++i) {
        float4 x = X4[lv[i] + tid];
        a[0].x += x.x; a[0].y += x.y; a[0].z += x.z; a[0].w += x.w;
    }
#pragma unroll
    for (int u = 4; u > 0; u >>= 1)
#pragma unroll
        for (int q = 0; q < u; ++q) {
            a[q].x += a[q + u].x; a[q].y += a[q + u].y;
            a[q].z += a[q + u].z; a[q].w += a[q + u].w;
        }
    float inv = tc > 0 ? 1.0f / (float)tc : 1.0f;
    float4 val = {a[0].x * inv, a[0].y * inv, a[0].z * inv, a[0].w * inv};
    const float4* W4 = (const float4*)Wc;
    float4 w0 = W4[tid], w1 = W4[64 + tid];
    float p0 = val.x * w0.x + val.y * w0.y + val.z * w0.z + val.w * w0.w;
    float p1 = val.x * w1.x + val.y * w1.y + val.z * w1.z + val.w * w1.w;
#pragma unroll
    for (int o = 32; o > 0; o >>= 1) {
        p0 += __shfl_down(p0, o, 64);
        p1 += __shfl_down(p1, o, 64);
    }
    if (tid == 0) {
        float l0 = p0 + bc[0], l1 = p1 + bc[1];
        float mx = fmaxf(l0, l1);
        float e0 = expf(l0 - mx), e1 = expf(l1 - mx);
        float s = 1.0f / (e0 + e1);
        out[e * 2 + 0] = e0 * s;
        out[e * 2 + 1] = e1 * s;
    }
}

extern "C" void kernel_launch(void* const* d_in, const int* in_sizes, int n_in,
                              void* d_out, int out_size, void* d_ws, size_t ws_size,
                              hipStream_t stream) {
    const float* X  = (const float*)d_in[0];
    const float* H  = (const float*)d_in[1];
    const float* Wp = (const float*)d_in[2];
    const float* W0 = (const float*)d_in[3];
    const float* W1 = (const float*)d_in[4];
    const float* g0 = (const float*)d_in[5];
    const float* b0 = (const float*)d_in[6];
    const float* g1 = (const float*)d_in[7];
    const float* b1 = (const float*)d_in[8];
    const float* Wc = (const float*)d_in[9];
    const float* bc = (const float*)d_in[10];
    float* out = (float*)d_out;

    float* ws = (float*)d_ws;
    float* Xh  = ws + OFF_XH;
    float* Z   = ws + OFF_Z;
    float* Y   = ws + OFF_Y;
    int* node_cnt  = (int*)(ws + OFF_NCNT);
    int* edge_cnt  = (int*)(ws + OFF_ECNT);
    int* edge_list = (int*)(ws + OFF_EL);
    int* node_list = (int*)(ws + OFF_NL);
    unsigned short* Xhb = (unsigned short*)(ws + OFF_XHB);

    hipMemsetAsync(edge_cnt, 0, (size_t)(NE * 16) * sizeof(int), stream);

    // fused: proj GEMM (blocks 0..255) + H scan (blocks 256..2303, wave-per-row)
    scan_proj<<<NPROJ + NSCAN, 256, 0, stream>>>(H, X, Wp, Xh, Xhb,
                                                 edge_cnt, node_cnt, edge_list, node_list);

    const float* Ws[2] = {W0, W1};
    const float* gs[2] = {g0, g1};
    const float* bs[2] = {b0, b1};
    for (int l = 0; l < 2; ++l) {
        edge_gather<<<NE, 64, 0, stream>>>(Xhb, edge_cnt, edge_list, node_cnt, Y);
        node_gather<<<NV, 64, 0, stream>>>(Y, node_cnt, node_list, edge_cnt, Z);
        gemm_relu_res_ln<<<NV / 32, 256, 0, stream>>>(Z, Ws[l], Xh, Xhb, gs[l], bs[l]);
    }

    pool_classify<<<NE, 64, 0, stream>>>(Xh, edge_cnt, edge_list, Wc, bc, out);
}

// Round 10
// 309.356 us; speedup vs baseline: 2.1389x; 1.0030x over previous
//
#include <hip/hip_runtime.h>
#include <math.h>

#define NV 8192
#define NE 4096
#define DIN 512
#define DH 256
#define CAP_E 96
#define CAP_V 64
#define NPROJ (NV / 32)      // 256 proj-GEMM blocks
#define NSCAN (NV / 2)       // 4096 scan blocks (4 waves/block, wave-per-HALF-row)

// ---------------- workspace layout (float offsets) ----------------
#define OFF_XH   0                       // V*DH fp32
#define OFF_Z    (OFF_XH + NV*DH)        // V*DH fp32
#define OFF_Y    (OFF_Z  + NV*DH)        // E*DH fp32
#define OFF_NCNT (OFF_Y  + NE*DH)        // V ints  (atomic-reserved bases = degrees)
#define OFF_ECNT (OFF_NCNT + NV)         // E*16 ints (line-padded counters)
#define OFF_EL   (OFF_ECNT + NE*16)      // E*CAP_E ints
#define OFF_NL   (OFF_EL + NE*CAP_E)     // V*CAP_V ints
#define OFF_XHB  (OFF_NL + NV*CAP_V)     // V*DH bf16 (= V*DH/2 floats)

using bf16x8 = __attribute__((ext_vector_type(8))) short;
using f32x4  = __attribute__((ext_vector_type(4))) float;

__device__ inline unsigned short f2bf(float f) {   // round-to-nearest-even
    union { float f; unsigned u; } v; v.f = f;
    unsigned r = v.u + 0x7FFF + ((v.u >> 16) & 1);
    return (unsigned short)(r >> 16);
}
__device__ inline float b2f(unsigned short s) {
    union { unsigned u; float f; } v; v.u = ((unsigned)s) << 16; return v.f;
}

// ---- fused: blocks [0,NPROJ) proj GEMM Xh = X @ Wp^T (BK=32);
//      blocks [NPROJ, NPROJ+NSCAN): scan H, wave-per-half-row, batched atomics ----
__global__ __launch_bounds__(256) void scan_proj(const float* __restrict__ H,
                                                 const float* __restrict__ X,
                                                 const float* __restrict__ Wp,
                                                 float* __restrict__ Xh,
                                                 unsigned short* __restrict__ Xhb,
                                                 int* __restrict__ edge_cnt,
                                                 int* __restrict__ node_cnt,
                                                 int* __restrict__ edge_list,
                                                 int* __restrict__ node_list) {
    __shared__ short AsBs[1024 + 8192];    // proj GEMM staging only (scan uses none)
    const int tid = threadIdx.x;
    if (blockIdx.x >= NPROJ) {
        // -------- scan path: one WAVE per half-row (2048 cols), no LDS --------
        const int w = tid >> 6, lane = tid & 63;
        const int v    = (blockIdx.x - NPROJ) * 2 + (w >> 1);
        const int half = w & 1;
        const float4* H4 = (const float4*)(H + (size_t)v * NE) + half * 512;
        float4 h[8];
#pragma unroll
        for (int it = 0; it < 8; ++it) h[it] = H4[lane + 64 * it];   // 8 indep 1KB loads
        // per-lane 32-bit hit mask (bit j=it*4+c -> edge half*2048 + 256*it + 4*lane + c)
        unsigned m = 0u;
#pragma unroll
        for (int it = 0; it < 8; ++it) {
            float hv[4] = {h[it].x, h[it].y, h[it].z, h[it].w};
#pragma unroll
            for (int c = 0; c < 4; ++c)
                m |= (hv[c] != 0.0f ? 1u : 0u) << (it * 4 + c);
        }
        int n = __builtin_popcount(m);
        // wave prefix-sum -> placement offsets within this wave's reservation
        int pre = n;
#pragma unroll
        for (int o = 1; o < 64; o <<= 1) {
            int t = __shfl_up(pre, o, 64);
            if (lane >= o) pre += t;
        }
        int total = __shfl(pre, 63, 64);
        int local = pre - n;
        // reserve a contiguous range in node_list[v] (1 atomic per wave; 2 waves/row)
        int base = 0;
        if (lane == 0 && total > 0) base = atomicAdd(&node_cnt[v], total);
        base = __shfl(base, 0, 64) + local;
        const int ebase = half * 2048 + 4 * lane;
        // extract up to 4 hits into registers
        int e_arr[4] = {0, 0, 0, 0};
        {
            unsigned mm = m;
#pragma unroll
            for (int u = 0; u < 4; ++u) {
                if (mm) {
                    int j = __builtin_ctz(mm);
                    mm &= mm - 1;
                    e_arr[u] = ebase + 256 * (j >> 2) + (j & 3);
                }
            }
        }
        // 4 independent predicated atomics (one latency window), then stores
        int s_arr[4];
#pragma unroll
        for (int u = 0; u < 4; ++u)
            s_arr[u] = (u < n) ? atomicAdd(&edge_cnt[e_arr[u] << 4], 1) : 0;
#pragma unroll
        for (int u = 0; u < 4; ++u) {
            if (u < n) {
                if (s_arr[u] < CAP_E) edge_list[e_arr[u] * CAP_E + s_arr[u]] = v;
                int idx = base + u;
                if (idx < CAP_V) node_list[v * CAP_V + idx] = e_arr[u];
            }
        }
        // rare overflow (n > 4)
        if (n > 4) {
            unsigned mm = m;
            mm &= mm - 1; mm &= mm - 1; mm &= mm - 1; mm &= mm - 1;
            int k = 4;
            while (mm) {
                int j = __builtin_ctz(mm); mm &= mm - 1;
                int ee = ebase + 256 * (j >> 2) + (j & 3);
                int gc = atomicAdd(&edge_cnt[ee << 4], 1);
                if (gc < CAP_E) edge_list[ee * CAP_E + gc] = v;
                int idx = base + k;
                if (idx < CAP_V) node_list[v * CAP_V + idx] = ee;
                ++k;
            }
        }
        return;
    }
    // ---------------- proj GEMM path: BM=32, BN=256, BK=32, K=DIN ----------------
    short* As = AsBs;
    short* Bs = AsBs + 1024;
    const int K = DIN;
    const int lane = tid & 63;
    const int w    = tid >> 6;
    const int bm   = blockIdx.x * 32;
    const int swz  = lane ^ ((lane >> 3) & 6);
    float4 ar, br[8];
    ar = *(const float4*)(X + (size_t)(bm + (tid >> 3)) * K + ((tid & 7) << 2));
#pragma unroll
    for (int it = 0; it < 8; ++it) {
        int i = tid + it * 256;
        br[it] = *(const float4*)(Wp + (size_t)(i >> 3) * K + ((i & 7) << 2));
    }
    f32x4 acc[2][4];
#pragma unroll
    for (int mi = 0; mi < 2; ++mi)
#pragma unroll
        for (int ni = 0; ni < 4; ++ni) acc[mi][ni] = (f32x4){0.f, 0.f, 0.f, 0.f};
    for (int k0 = 0; k0 < K; k0 += 32) {
        __syncthreads();
        {   // stage A: 32x32, one float4/thread
            int row = tid >> 3, kk = (tid & 7) << 2;
            int quad = kk >> 3, j = kk & 7;
            int ln = (row & 15) + (quad << 4);
            int pp = ln ^ ((ln >> 3) & 6);
            ushort4 u = {f2bf(ar.x), f2bf(ar.y), f2bf(ar.z), f2bf(ar.w)};
            *(ushort4*)&As[(row >> 4) * 512 + pp * 8 + j] = u;
        }
#pragma unroll
        for (int it = 0; it < 8; ++it) {   // stage B: 256x32
            int i = tid + it * 256;
            int row = i >> 3, kk = (i & 7) << 2;
            int quad = kk >> 3, j = kk & 7;
            int ln = (row & 15) + (quad << 4);
            int pp = ln ^ ((ln >> 3) & 6);
            float4 v = br[it];
            ushort4 u = {f2bf(v.x), f2bf(v.y), f2bf(v.z), f2bf(v.w)};
            *(ushort4*)&Bs[(row >> 4) * 512 + pp * 8 + j] = u;
        }
        __syncthreads();
        if (k0 + 32 < K) {
            int kn = k0 + 32;
            ar = *(const float4*)(X + (size_t)(bm + (tid >> 3)) * K + kn + ((tid & 7) << 2));
#pragma unroll
            for (int it = 0; it < 8; ++it) {
                int i = tid + it * 256;
                br[it] = *(const float4*)(Wp + (size_t)(i >> 3) * K + kn + ((i & 7) << 2));
            }
        }
        bf16x8 af[2], bfr[4];
        af[0] = *(const bf16x8*)&As[0 * 512 + swz * 8];
        af[1] = *(const bf16x8*)&As[1 * 512 + swz * 8];
#pragma unroll
        for (int ni = 0; ni < 4; ++ni)
            bfr[ni] = *(const bf16x8*)&Bs[(w * 4 + ni) * 512 + swz * 8];
#pragma unroll
        for (int mi = 0; mi < 2; ++mi)
#pragma unroll
            for (int ni = 0; ni < 4; ++ni)
                acc[mi][ni] = __builtin_amdgcn_mfma_f32_16x16x32_bf16(
                    af[mi], bfr[ni], acc[mi][ni], 0, 0, 0);
    }
    const int quad = lane >> 4, cl = lane & 15;
#pragma unroll
    for (int mi = 0; mi < 2; ++mi)
#pragma unroll
        for (int ni = 0; ni < 4; ++ni)
#pragma unroll
            for (int r = 0; r < 4; ++r) {
                float v = acc[mi][ni][r];
                size_t idx = (size_t)(bm + mi * 16 + quad * 4 + r) * DH + w * 64 + ni * 16 + cl;
                Xh[idx] = v;
                Xhb[idx] = f2bf(v);
            }
}

// ------- fused: Xh = LayerNorm(Xh + relu(Z @ W^T)) * g + b; also writes Xhb ----
__global__ __launch_bounds__(256) void gemm_relu_res_ln(const float* __restrict__ Z,
                                                        const float* __restrict__ W,
                                                        float* __restrict__ Xh,
                                                        unsigned short* __restrict__ Xhb,
                                                        const float* __restrict__ g,
                                                        const float* __restrict__ b) {
    const int K = DH;
    __shared__ short As[2048];
    __shared__ short Bs[16384];
    __shared__ float redS[32][4];
    __shared__ float redQ[32][4];
    const int tid  = threadIdx.x;
    const int lane = tid & 63;
    const int w    = tid >> 6;
    const int bm   = blockIdx.x * 32;
    const int swz  = lane ^ ((lane >> 3) & 6);

    float4 ar[2], br[16];
    {
        int i0 = tid, i1 = tid + 256;
        ar[0] = *(const float4*)(Z + (size_t)(bm + (i0 >> 4)) * K + ((i0 & 15) << 2));
        ar[1] = *(const float4*)(Z + (size_t)(bm + (i1 >> 4)) * K + ((i1 & 15) << 2));
#pragma unroll
        for (int it = 0; it < 16; ++it) {
            int i = tid + it * 256;
            br[it] = *(const float4*)(W + (size_t)(i >> 4) * K + ((i & 15) << 2));
        }
    }
    f32x4 acc[2][4];
#pragma unroll
    for (int mi = 0; mi < 2; ++mi)
#pragma unroll
        for (int ni = 0; ni < 4; ++ni) acc[mi][ni] = (f32x4){0.f, 0.f, 0.f, 0.f};

    for (int k0 = 0; k0 < K; k0 += 64) {
        __syncthreads();
#pragma unroll
        for (int s = 0; s < 2; ++s) {
            int i = tid + s * 256;
            int row = i >> 4, kk = (i & 15) << 2;
            int kc = kk >> 5, quad = (kk >> 3) & 3, j = kk & 7;
            int ln = (row & 15) + (quad << 4);
            int pp = ln ^ ((ln >> 3) & 6);
            float4 v = ar[s];
            ushort4 u = {f2bf(v.x), f2bf(v.y), f2bf(v.z), f2bf(v.w)};
            *(ushort4*)&As[((row >> 4) * 2 + kc) * 512 + pp * 8 + j] = u;
        }
#pragma unroll
        for (int it = 0; it < 16; ++it) {
            int i = tid + it * 256;
            int row = i >> 4, kk = (i & 15) << 2;
            int kc = kk >> 5, quad = (kk >> 3) & 3, j = kk & 7;
            int ln = (row & 15) + (quad << 4);
            int pp = ln ^ ((ln >> 3) & 6);
            float4 v = br[it];
            ushort4 u = {f2bf(v.x), f2bf(v.y), f2bf(v.z), f2bf(v.w)};
            *(ushort4*)&Bs[((row >> 4) * 2 + kc) * 512 + pp * 8 + j] = u;
        }
        __syncthreads();
        if (k0 + 64 < K) {
            int kn = k0 + 64;
            int i0 = tid, i1 = tid + 256;
            ar[0] = *(const float4*)(Z + (size_t)(bm + (i0 >> 4)) * K + kn + ((i0 & 15) << 2));
            ar[1] = *(const float4*)(Z + (size_t)(bm + (i1 >> 4)) * K + kn + ((i1 & 15) << 2));
#pragma unroll
            for (int it = 0; it < 16; ++it) {
                int i = tid + it * 256;
                br[it] = *(const float4*)(W + (size_t)(i >> 4) * K + kn + ((i & 15) << 2));
            }
        }
#pragma unroll
        for (int kc = 0; kc < 2; ++kc) {
            bf16x8 af[2], bfr[4];
            af[0] = *(const bf16x8*)&As[(0 * 2 + kc) * 512 + swz * 8];
            af[1] = *(const bf16x8*)&As[(1 * 2 + kc) * 512 + swz * 8];
#pragma unroll
            for (int ni = 0; ni < 4; ++ni)
                bfr[ni] = *(const bf16x8*)&Bs[((w * 4 + ni) * 2 + kc) * 512 + swz * 8];
#pragma unroll
            for (int mi = 0; mi < 2; ++mi)
#pragma unroll
                for (int ni = 0; ni < 4; ++ni)
                    acc[mi][ni] = __builtin_amdgcn_mfma_f32_16x16x32_bf16(
                        af[mi], bfr[ni], acc[mi][ni], 0, 0, 0);
        }
    }
    const int quad = lane >> 4, cl = lane & 15;
#pragma unroll
    for (int mi = 0; mi < 2; ++mi)
#pragma unroll
        for (int r = 0; r < 4; ++r) {
            int row = bm + mi * 16 + quad * 4 + r;
            float s = 0.f, q = 0.f;
#pragma unroll
            for (int ni = 0; ni < 4; ++ni) {
                int col = w * 64 + ni * 16 + cl;
                float v = fmaxf(acc[mi][ni][r], 0.f) + Xh[(size_t)row * DH + col];
                acc[mi][ni][r] = v;
                s += v; q = fmaf(v, v, q);
            }
#pragma unroll
            for (int o = 1; o < 16; o <<= 1) {
                s += __shfl_xor(s, o, 64);
                q += __shfl_xor(q, o, 64);
            }
            if (cl == 0) {
                redS[mi * 16 + quad * 4 + r][w] = s;
                redQ[mi * 16 + quad * 4 + r][w] = q;
            }
        }
    __syncthreads();
#pragma unroll
    for (int mi = 0; mi < 2; ++mi)
#pragma unroll
        for (int r = 0; r < 4; ++r) {
            int R = mi * 16 + quad * 4 + r;
            float s = redS[R][0] + redS[R][1] + redS[R][2] + redS[R][3];
            float q = redQ[R][0] + redQ[R][1] + redQ[R][2] + redQ[R][3];
            float m = s * (1.0f / DH);
            float var = q * (1.0f / DH) - m * m;
            float rstd = rsqrtf(var + 1e-5f);
            int row = bm + R;
#pragma unroll
            for (int ni = 0; ni < 4; ++ni) {
                int col = w * 64 + ni * 16 + cl;
                float v = (acc[mi][ni][r] - m) * rstd * g[col] + b[col];
                size_t idx = (size_t)row * DH + col;
                Xh[idx] = v;
                Xhb[idx] = f2bf(v);
            }
        }
}

// ---- Y[e,:] = rsqrt(de) * sum_{v in e} rsqrt(dv) * Xhb[v,:]  (bf16 src, 64 thr) ----
__global__ __launch_bounds__(64) void edge_gather(const unsigned short* __restrict__ Xhb,
                                                  const int* __restrict__ edge_cnt,
                                                  const int* __restrict__ edge_list,
                                                  const int* __restrict__ node_cnt,
                                                  float* __restrict__ Y) {
    int e = blockIdx.x;
    int tid = threadIdx.x;
    __shared__ int   lv[CAP_E];
    __shared__ float lc[CAP_E];
    int tc = edge_cnt[e << 4];
    int cnt = min(tc, CAP_E);
    for (int j = tid; j < cnt; j += 64) {
        int v = edge_list[e * CAP_E + j];
        lv[j] = v * (DH / 4);
        lc[j] = rsqrtf((float)node_cnt[v]);
    }
    __syncthreads();
    const ushort4* X4 = (const ushort4*)Xhb;
    float4 a[8];
#pragma unroll
    for (int u = 0; u < 8; ++u) a[u] = (float4){0.f, 0.f, 0.f, 0.f};
    int i = 0;
    for (; i + 8 <= cnt; i += 8) {
#pragma unroll
        for (int u = 0; u < 8; ++u) {
            ushort4 h = X4[lv[i + u] + tid]; float c = lc[i + u];
            a[u].x = fmaf(c, b2f(h.x), a[u].x); a[u].y = fmaf(c, b2f(h.y), a[u].y);
            a[u].z = fmaf(c, b2f(h.z), a[u].z); a[u].w = fmaf(c, b2f(h.w), a[u].w);
        }
    }
    for (; i < cnt; ++i) {
        ushort4 h = X4[lv[i] + tid]; float c = lc[i];
        a[0].x = fmaf(c, b2f(h.x), a[0].x); a[0].y = fmaf(c, b2f(h.y), a[0].y);
        a[0].z = fmaf(c, b2f(h.z), a[0].z); a[0].w = fmaf(c, b2f(h.w), a[0].w);
    }
#pragma unroll
    for (int u = 4; u > 0; u >>= 1)
#pragma unroll
        for (int q = 0; q < u; ++q) {
            a[q].x += a[q + u].x; a[q].y += a[q + u].y;
            a[q].z += a[q + u].z; a[q].w += a[q + u].w;
        }
    float de = tc > 0 ? rsqrtf((float)tc) : 0.f;
    float4 o = {de * a[0].x, de * a[0].y, de * a[0].z, de * a[0].w};
    ((float4*)Y)[e * (DH / 4) + tid] = o;
}

// ---- Z[v,:] = rsqrt(dv) * sum_{e ∋ v} rsqrt(de) * Y[e,:]  (fp32 src, 64 thr) ----
__global__ __launch_bounds__(64) void node_gather(const float* __restrict__ Y,
                                                  const int* __restrict__ node_cnt,
                                                  const int* __restrict__ node_list,
                                                  const int* __restrict__ edge_cnt,
                                                  float* __restrict__ Z) {
    int v = blockIdx.x;
    int tid = threadIdx.x;
    __shared__ int   le[CAP_V];
    __shared__ float lc[CAP_V];
    int tc = node_cnt[v];
    int cnt = min(tc, CAP_V);
    if (tid < cnt) {
        int e = node_list[v * CAP_V + tid];
        le[tid] = e * (DH / 4);
        lc[tid] = rsqrtf((float)edge_cnt[e << 4]);
    }
    __syncthreads();
    const float4* Y4 = (const float4*)Y;
    float4 a[8];
#pragma unroll
    for (int u = 0; u < 8; ++u) a[u] = (float4){0.f, 0.f, 0.f, 0.f};
    int i = 0;
    for (; i + 8 <= cnt; i += 8) {
#pragma unroll
        for (int u = 0; u < 8; ++u) {
            float4 x = Y4[le[i + u] + tid]; float c = lc[i + u];
            a[u].x = fmaf(c, x.x, a[u].x); a[u].y = fmaf(c, x.y, a[u].y);
            a[u].z = fmaf(c, x.z, a[u].z); a[u].w = fmaf(c, x.w, a[u].w);
        }
    }
    for (; i < cnt; ++i) {
        float4 x = Y4[le[i] + tid]; float c = lc[i];
        a[0].x = fmaf(c, x.x, a[0].x); a[0].y = fmaf(c, x.y, a[0].y);
        a[0].z = fmaf(c, x.z, a[0].z); a[0].w = fmaf(c, x.w, a[0].w);
    }
#pragma unroll
    for (int u = 4; u > 0; u >>= 1)
#pragma unroll
        for (int q = 0; q < u; ++q) {
            a[q].x += a[q + u].x; a[q].y += a[q + u].y;
            a[q].z += a[q + u].z; a[q].w += a[q + u].w;
        }
    float dv = tc > 0 ? rsqrtf((float)tc) : 0.f;
    float4 o = {dv * a[0].x, dv * a[0].y, dv * a[0].z, dv * a[0].w};
    ((float4*)Z)[v * (DH / 4) + tid] = o;
}

// ------- fused mean-pool + classifier + softmax (64 thr, bf16 src) -------
__global__ __launch_bounds__(64) void pool_classify(const unsigned short* __restrict__ Xhb,
                                                    const int* __restrict__ edge_cnt,
                                                    const int* __restrict__ edge_list,
                                                    const float* __restrict__ Wc,
                                                    const float* __restrict__ bc,
                                                    float* __restrict__ out) {
    int e = blockIdx.x;
    int tid = threadIdx.x;
    __shared__ int lv[CAP_E];
    int tc = edge_cnt[e << 4];
    int cnt = min(tc, CAP_E);
    for (int j = tid; j < cnt; j += 64) lv[j] = edge_list[e * CAP_E + j] * (DH / 4);
    __syncthreads();
    const ushort4* X4 = (const ushort4*)Xhb;
    float4 a[8];
#pragma unroll
    for (int u = 0; u < 8; ++u) a[u] = (float4){0, 0, 0, 0};
    int i = 0;
    for (; i + 8 <= cnt; i += 8) {
#pragma unroll
        for (int u = 0; u < 8; ++u) {
            ushort4 h = X4[lv[i + u] + tid];
            a[u].x += b2f(h.x); a[u].y += b2f(h.y);
            a[u].z += b2f(h.z); a[u].w += b2f(h.w);
        }
    }
    for (; i < cnt; ++i) {
        ushort4 h = X4[lv[i] + tid];
        a[0].x += b2f(h.x); a[0].y += b2f(h.y);
        a[0].z += b2f(h.z); a[0].w += b2f(h.w);
    }
#pragma unroll
    for (int u = 4; u > 0; u >>= 1)
#pragma unroll
        for (int q = 0; q < u; ++q) {
            a[q].x += a[q + u].x; a[q].y += a[q + u].y;
            a[q].z += a[q + u].z; a[q].w += a[q + u].w;
        }
    float inv = tc > 0 ? 1.0f / (float)tc : 1.0f;
    float4 val = {a[0].x * inv, a[0].y * inv, a[0].z * inv, a[0].w * inv};
    const float4* W4 = (const float4*)Wc;
    float4 w0 = W4[tid], w1 = W4[64 + tid];
    float p0 = val.x * w0.x + val.y * w0.y + val.z * w0.z + val.w * w0.w;
    float p1 = val.x * w1.x + val.y * w1.y + val.z * w1.z + val.w * w1.w;
#pragma unroll
    for (int o = 32; o > 0; o >>= 1) {
        p0 += __shfl_down(p0, o, 64);
        p1 += __shfl_down(p1, o, 64);
    }
    if (tid == 0) {
        float l0 = p0 + bc[0], l1 = p1 + bc[1];
        float mx = fmaxf(l0, l1);
        float e0 = expf(l0 - mx), e1 = expf(l1 - mx);
        float s = 1.0f / (e0 + e1);
        out[e * 2 + 0] = e0 * s;
        out[e * 2 + 1] = e1 * s;
    }
}

extern "C" void kernel_launch(void* const* d_in, const int* in_sizes, int n_in,
                              void* d_out, int out_size, void* d_ws, size_t ws_size,
                              hipStream_t stream) {
    const float* X  = (const float*)d_in[0];
    const float* H  = (const float*)d_in[1];
    const float* Wp = (const float*)d_in[2];
    const float* W0 = (const float*)d_in[3];
    const float* W1 = (const float*)d_in[4];
    const float* g0 = (const float*)d_in[5];
    const float* b0 = (const float*)d_in[6];
    const float* g1 = (const float*)d_in[7];
    const float* b1 = (const float*)d_in[8];
    const float* Wc = (const float*)d_in[9];
    const float* bc = (const float*)d_in[10];
    float* out = (float*)d_out;

    float* ws = (float*)d_ws;
    float* Xh  = ws + OFF_XH;
    float* Z   = ws + OFF_Z;
    float* Y   = ws + OFF_Y;
    int* node_cnt  = (int*)(ws + OFF_NCNT);
    int* edge_cnt  = (int*)(ws + OFF_ECNT);
    int* edge_list = (int*)(ws + OFF_EL);
    int* node_list = (int*)(ws + OFF_NL);
    unsigned short* Xhb = (unsigned short*)(ws + OFF_XHB);

    // node_cnt and edge_cnt are contiguous: one memset for both
    hipMemsetAsync(node_cnt, 0, (size_t)(NV + NE * 16) * sizeof(int), stream);

    // fused: proj GEMM (blocks 0..255) + H scan (wave-per-half-row)
    scan_proj<<<NPROJ + NSCAN, 256, 0, stream>>>(H, X, Wp, Xh, Xhb,
                                                 edge_cnt, node_cnt, edge_list, node_list);

    const float* Ws[2] = {W0, W1};
    const float* gs[2] = {g0, g1};
    const float* bs[2] = {b0, b1};
    for (int l = 0; l < 2; ++l) {
        edge_gather<<<NE, 64, 0, stream>>>(Xhb, edge_cnt, edge_list, node_cnt, Y);
        node_gather<<<NV, 64, 0, stream>>>(Y, node_cnt, node_list, edge_cnt, Z);
        gemm_relu_res_ln<<<NV / 32, 256, 0, stream>>>(Z, Ws[l], Xh, Xhb, gs[l], bs[l]);
    }

    pool_classify<<<NE, 64, 0, stream>>>(Xhb, edge_cnt, edge_list, Wc, bc, out);
}

// Round 11
// 299.688 us; speedup vs baseline: 2.2079x; 1.0323x over previous
//
#include <hip/hip_runtime.h>
#include <math.h>

#define NV 8192
#define NE 4096
#define DIN 512
#define DH 256
#define CAP_E 96
#define CAP_V 64
#define NPROJ (NV / 32)      // 256 proj-GEMM blocks
#define NSCAN (NV / 2)       // 4096 scan blocks (4 waves/block, wave-per-half-row)

// ---------------- workspace layout (float offsets) ----------------
#define OFF_XH   0                       // V*DH fp32 (residual)
#define OFF_UB   (OFF_XH + NV*DH)        // V*DH bf16 (U = Xh@W^T)
#define OFF_YB   (OFF_UB + NV*DH/2)      // E*DH bf16
#define OFF_NCNT (OFF_YB + NE*DH/2)      // V ints
#define OFF_ECNT (OFF_NCNT + NV)         // E*16 ints (line-padded counters)
#define OFF_EL   (OFF_ECNT + NE*16)      // E*CAP_E ints
#define OFF_NL   (OFF_EL + NE*CAP_E)     // V*CAP_V ints
#define OFF_XHB  (OFF_NL + NV*CAP_V)     // V*DH bf16

using bf16x8 = __attribute__((ext_vector_type(8))) short;
using f32x4  = __attribute__((ext_vector_type(4))) float;

__device__ inline unsigned short f2bf(float f) {   // round-to-nearest-even
    union { float f; unsigned u; } v; v.f = f;
    unsigned r = v.u + 0x7FFF + ((v.u >> 16) & 1);
    return (unsigned short)(r >> 16);
}
__device__ inline float b2f(unsigned short s) {
    union { unsigned u; float f; } v; v.u = ((unsigned)s) << 16; return v.f;
}

// ---- fused: blocks [0,NPROJ) proj GEMM Xh = X @ Wp^T (BK=32);
//      blocks [NPROJ, NPROJ+NSCAN): scan H, wave-per-half-row, batched atomics ----
__global__ __launch_bounds__(256) void scan_proj(const float* __restrict__ H,
                                                 const float* __restrict__ X,
                                                 const float* __restrict__ Wp,
                                                 float* __restrict__ Xh,
                                                 unsigned short* __restrict__ Xhb,
                                                 int* __restrict__ edge_cnt,
                                                 int* __restrict__ node_cnt,
                                                 int* __restrict__ edge_list,
                                                 int* __restrict__ node_list) {
    __shared__ short AsBs[1024 + 8192];
    const int tid = threadIdx.x;
    if (blockIdx.x >= NPROJ) {
        const int w = tid >> 6, lane = tid & 63;
        const int v    = (blockIdx.x - NPROJ) * 2 + (w >> 1);
        const int half = w & 1;
        const float4* H4 = (const float4*)(H + (size_t)v * NE) + half * 512;
        float4 h[8];
#pragma unroll
        for (int it = 0; it < 8; ++it) h[it] = H4[lane + 64 * it];
        unsigned m = 0u;
#pragma unroll
        for (int it = 0; it < 8; ++it) {
            float hv[4] = {h[it].x, h[it].y, h[it].z, h[it].w};
#pragma unroll
            for (int c = 0; c < 4; ++c)
                m |= (hv[c] != 0.0f ? 1u : 0u) << (it * 4 + c);
        }
        int n = __builtin_popcount(m);
        int pre = n;
#pragma unroll
        for (int o = 1; o < 64; o <<= 1) {
            int t = __shfl_up(pre, o, 64);
            if (lane >= o) pre += t;
        }
        int total = __shfl(pre, 63, 64);
        int local = pre - n;
        int base = 0;
        if (lane == 0 && total > 0) base = atomicAdd(&node_cnt[v], total);
        base = __shfl(base, 0, 64) + local;
        const int ebase = half * 2048 + 4 * lane;
        int e_arr[4] = {0, 0, 0, 0};
        {
            unsigned mm = m;
#pragma unroll
            for (int u = 0; u < 4; ++u) {
                if (mm) {
                    int j = __builtin_ctz(mm);
                    mm &= mm - 1;
                    e_arr[u] = ebase + 256 * (j >> 2) + (j & 3);
                }
            }
        }
        int s_arr[4];
#pragma unroll
        for (int u = 0; u < 4; ++u)
            s_arr[u] = (u < n) ? atomicAdd(&edge_cnt[e_arr[u] << 4], 1) : 0;
#pragma unroll
        for (int u = 0; u < 4; ++u) {
            if (u < n) {
                if (s_arr[u] < CAP_E) edge_list[e_arr[u] * CAP_E + s_arr[u]] = v;
                int idx = base + u;
                if (idx < CAP_V) node_list[v * CAP_V + idx] = e_arr[u];
            }
        }
        if (n > 4) {
            unsigned mm = m;
            mm &= mm - 1; mm &= mm - 1; mm &= mm - 1; mm &= mm - 1;
            int k = 4;
            while (mm) {
                int j = __builtin_ctz(mm); mm &= mm - 1;
                int ee = ebase + 256 * (j >> 2) + (j & 3);
                int gc = atomicAdd(&edge_cnt[ee << 4], 1);
                if (gc < CAP_E) edge_list[ee * CAP_E + gc] = v;
                int idx = base + k;
                if (idx < CAP_V) node_list[v * CAP_V + idx] = ee;
                ++k;
            }
        }
        return;
    }
    // ---------------- proj GEMM path: BM=32, BN=256, BK=32, K=DIN ----------------
    short* As = AsBs;
    short* Bs = AsBs + 1024;
    const int K = DIN;
    const int lane = tid & 63;
    const int w    = tid >> 6;
    const int bm   = blockIdx.x * 32;
    const int swz  = lane ^ ((lane >> 3) & 6);
    float4 ar, br[8];
    ar = *(const float4*)(X + (size_t)(bm + (tid >> 3)) * K + ((tid & 7) << 2));
#pragma unroll
    for (int it = 0; it < 8; ++it) {
        int i = tid + it * 256;
        br[it] = *(const float4*)(Wp + (size_t)(i >> 3) * K + ((i & 7) << 2));
    }
    f32x4 acc[2][4];
#pragma unroll
    for (int mi = 0; mi < 2; ++mi)
#pragma unroll
        for (int ni = 0; ni < 4; ++ni) acc[mi][ni] = (f32x4){0.f, 0.f, 0.f, 0.f};
    for (int k0 = 0; k0 < K; k0 += 32) {
        __syncthreads();
        {
            int row = tid >> 3, kk = (tid & 7) << 2;
            int quad = kk >> 3, j = kk & 7;
            int ln = (row & 15) + (quad << 4);
            int pp = ln ^ ((ln >> 3) & 6);
            ushort4 u = {f2bf(ar.x), f2bf(ar.y), f2bf(ar.z), f2bf(ar.w)};
            *(ushort4*)&As[(row >> 4) * 512 + pp * 8 + j] = u;
        }
#pragma unroll
        for (int it = 0; it < 8; ++it) {
            int i = tid + it * 256;
            int row = i >> 3, kk = (i & 7) << 2;
            int quad = kk >> 3, j = kk & 7;
            int ln = (row & 15) + (quad << 4);
            int pp = ln ^ ((ln >> 3) & 6);
            float4 v = br[it];
            ushort4 u = {f2bf(v.x), f2bf(v.y), f2bf(v.z), f2bf(v.w)};
            *(ushort4*)&Bs[(row >> 4) * 512 + pp * 8 + j] = u;
        }
        __syncthreads();
        if (k0 + 32 < K) {
            int kn = k0 + 32;
            ar = *(const float4*)(X + (size_t)(bm + (tid >> 3)) * K + kn + ((tid & 7) << 2));
#pragma unroll
            for (int it = 0; it < 8; ++it) {
                int i = tid + it * 256;
                br[it] = *(const float4*)(Wp + (size_t)(i >> 3) * K + kn + ((i & 7) << 2));
            }
        }
        bf16x8 af[2], bfr[4];
        af[0] = *(const bf16x8*)&As[0 * 512 + swz * 8];
        af[1] = *(const bf16x8*)&As[1 * 512 + swz * 8];
#pragma unroll
        for (int ni = 0; ni < 4; ++ni)
            bfr[ni] = *(const bf16x8*)&Bs[(w * 4 + ni) * 512 + swz * 8];
#pragma unroll
        for (int mi = 0; mi < 2; ++mi)
#pragma unroll
            for (int ni = 0; ni < 4; ++ni)
                acc[mi][ni] = __builtin_amdgcn_mfma_f32_16x16x32_bf16(
                    af[mi], bfr[ni], acc[mi][ni], 0, 0, 0);
    }
    const int quad = lane >> 4, cl = lane & 15;
#pragma unroll
    for (int mi = 0; mi < 2; ++mi)
#pragma unroll
        for (int ni = 0; ni < 4; ++ni)
#pragma unroll
            for (int r = 0; r < 4; ++r) {
                float v = acc[mi][ni][r];
                size_t idx = (size_t)(bm + mi * 16 + quad * 4 + r) * DH + w * 64 + ni * 16 + cl;
                Xh[idx] = v;
                Xhb[idx] = f2bf(v);
            }
}

// ------- U = bf16(Xhb @ W^T): bf16 A (no conversion), K=256, BM=32 ----------
__global__ __launch_bounds__(256) void gemm_u(const unsigned short* __restrict__ A,
                                              const float* __restrict__ W,
                                              unsigned short* __restrict__ U) {
    const int K = DH;
    __shared__ short As[2048];
    __shared__ short Bs[16384];
    const int tid  = threadIdx.x;
    const int lane = tid & 63;
    const int w    = tid >> 6;
    const int bm   = blockIdx.x * 32;
    const int swz  = lane ^ ((lane >> 3) & 6);

    uint4 ar; float4 br[16];
    ar = *(const uint4*)(A + (size_t)(bm + (tid >> 3)) * K + ((tid & 7) << 3));
#pragma unroll
    for (int it = 0; it < 16; ++it) {
        int i = tid + it * 256;
        br[it] = *(const float4*)(W + (size_t)(i >> 4) * K + ((i & 15) << 2));
    }
    f32x4 acc[2][4];
#pragma unroll
    for (int mi = 0; mi < 2; ++mi)
#pragma unroll
        for (int ni = 0; ni < 4; ++ni) acc[mi][ni] = (f32x4){0.f, 0.f, 0.f, 0.f};

    for (int k0 = 0; k0 < K; k0 += 64) {
        __syncthreads();
        {   // A: 32x64 bf16, one uint4 (8 bf16) per thread
            int row = tid >> 3, kq = tid & 7;
            int kc = kq >> 2, quad = kq & 3;
            int ln = (row & 15) + (quad << 4);
            int pp = ln ^ ((ln >> 3) & 6);
            *(uint4*)&As[((row >> 4) * 2 + kc) * 512 + pp * 8] = ar;
        }
#pragma unroll
        for (int it = 0; it < 16; ++it) {   // B: 256x64 fp32 -> bf16
            int i = tid + it * 256;
            int row = i >> 4, kk = (i & 15) << 2;
            int kc = kk >> 5, quad = (kk >> 3) & 3, j = kk & 7;
            int ln = (row & 15) + (quad << 4);
            int pp = ln ^ ((ln >> 3) & 6);
            float4 v = br[it];
            ushort4 u = {f2bf(v.x), f2bf(v.y), f2bf(v.z), f2bf(v.w)};
            *(ushort4*)&Bs[((row >> 4) * 2 + kc) * 512 + pp * 8 + j] = u;
        }
        __syncthreads();
        if (k0 + 64 < K) {
            int kn = k0 + 64;
            ar = *(const uint4*)(A + (size_t)(bm + (tid >> 3)) * K + kn + ((tid & 7) << 3));
#pragma unroll
            for (int it = 0; it < 16; ++it) {
                int i = tid + it * 256;
                br[it] = *(const float4*)(W + (size_t)(i >> 4) * K + kn + ((i & 15) << 2));
            }
        }
#pragma unroll
        for (int kc = 0; kc < 2; ++kc) {
            bf16x8 af[2], bfr[4];
            af[0] = *(const bf16x8*)&As[(0 * 2 + kc) * 512 + swz * 8];
            af[1] = *(const bf16x8*)&As[(1 * 2 + kc) * 512 + swz * 8];
#pragma unroll
            for (int ni = 0; ni < 4; ++ni)
                bfr[ni] = *(const bf16x8*)&Bs[((w * 4 + ni) * 2 + kc) * 512 + swz * 8];
#pragma unroll
            for (int mi = 0; mi < 2; ++mi)
#pragma unroll
                for (int ni = 0; ni < 4; ++ni)
                    acc[mi][ni] = __builtin_amdgcn_mfma_f32_16x16x32_bf16(
                        af[mi], bfr[ni], acc[mi][ni], 0, 0, 0);
        }
    }
    const int quad = lane >> 4, cl = lane & 15;
#pragma unroll
    for (int mi = 0; mi < 2; ++mi)
#pragma unroll
        for (int ni = 0; ni < 4; ++ni)
#pragma unroll
            for (int r = 0; r < 4; ++r)
                U[(size_t)(bm + mi * 16 + quad * 4 + r) * DH + w * 64 + ni * 16 + cl]
                    = f2bf(acc[mi][ni][r]);
}

// ---- Yb[e,:] = bf16( rsqrt(de) * sum_{v in e} rsqrt(dv) * Ub[v,:] ) ----
__global__ __launch_bounds__(64) void edge_gather(const unsigned short* __restrict__ Ub,
                                                  const int* __restrict__ edge_cnt,
                                                  const int* __restrict__ edge_list,
                                                  const int* __restrict__ node_cnt,
                                                  unsigned short* __restrict__ Yb) {
    int e = blockIdx.x;
    int tid = threadIdx.x;
    __shared__ int   lv[CAP_E];
    __shared__ float lc[CAP_E];
    int tc = edge_cnt[e << 4];
    int cnt = min(tc, CAP_E);
    for (int j = tid; j < cnt; j += 64) {
        int v = edge_list[e * CAP_E + j];
        lv[j] = v * (DH / 4);
        lc[j] = rsqrtf((float)node_cnt[v]);
    }
    __syncthreads();
    const ushort4* X4 = (const ushort4*)Ub;
    float4 a[8];
#pragma unroll
    for (int u = 0; u < 8; ++u) a[u] = (float4){0.f, 0.f, 0.f, 0.f};
    int i = 0;
    for (; i + 8 <= cnt; i += 8) {
#pragma unroll
        for (int u = 0; u < 8; ++u) {
            ushort4 h = X4[lv[i + u] + tid]; float c = lc[i + u];
            a[u].x = fmaf(c, b2f(h.x), a[u].x); a[u].y = fmaf(c, b2f(h.y), a[u].y);
            a[u].z = fmaf(c, b2f(h.z), a[u].z); a[u].w = fmaf(c, b2f(h.w), a[u].w);
        }
    }
    for (; i < cnt; ++i) {
        ushort4 h = X4[lv[i] + tid]; float c = lc[i];
        a[0].x = fmaf(c, b2f(h.x), a[0].x); a[0].y = fmaf(c, b2f(h.y), a[0].y);
        a[0].z = fmaf(c, b2f(h.z), a[0].z); a[0].w = fmaf(c, b2f(h.w), a[0].w);
    }
#pragma unroll
    for (int u = 4; u > 0; u >>= 1)
#pragma unroll
        for (int q = 0; q < u; ++q) {
            a[q].x += a[q + u].x; a[q].y += a[q + u].y;
            a[q].z += a[q + u].z; a[q].w += a[q + u].w;
        }
    float de = tc > 0 ? rsqrtf((float)tc) : 0.f;
    ushort4 o = {f2bf(de * a[0].x), f2bf(de * a[0].y),
                 f2bf(de * a[0].z), f2bf(de * a[0].w)};
    ((ushort4*)Yb)[e * (DH / 4) + tid] = o;
}

// ---- node gather + relu + residual + LayerNorm, one wave per row ----
// Xh = LN(Xh + relu( rsqrt(dv) * sum_{e ∋ v} rsqrt(de) * Yb[e,:] )) * g + b
__global__ __launch_bounds__(64) void node_ln(const unsigned short* __restrict__ Yb,
                                              const int* __restrict__ node_cnt,
                                              const int* __restrict__ node_list,
                                              const int* __restrict__ edge_cnt,
                                              float* __restrict__ Xh,
                                              unsigned short* __restrict__ Xhb,
                                              const float* __restrict__ g,
                                              const float* __restrict__ b) {
    int v = blockIdx.x;
    int tid = threadIdx.x;
    __shared__ int   le[CAP_V];
    __shared__ float lc[CAP_V];
    int tc = node_cnt[v];
    int cnt = min(tc, CAP_V);
    if (tid < cnt) {
        int e = node_list[v * CAP_V + tid];
        le[tid] = e * (DH / 4);
        lc[tid] = rsqrtf((float)edge_cnt[e << 4]);
    }
    __syncthreads();
    const ushort4* Y4 = (const ushort4*)Yb;
    float4 a[8];
#pragma unroll
    for (int u = 0; u < 8; ++u) a[u] = (float4){0.f, 0.f, 0.f, 0.f};
    int i = 0;
    for (; i + 8 <= cnt; i += 8) {
#pragma unroll
        for (int u = 0; u < 8; ++u) {
            ushort4 h = Y4[le[i + u] + tid]; float c = lc[i + u];
            a[u].x = fmaf(c, b2f(h.x), a[u].x); a[u].y = fmaf(c, b2f(h.y), a[u].y);
            a[u].z = fmaf(c, b2f(h.z), a[u].z); a[u].w = fmaf(c, b2f(h.w), a[u].w);
        }
    }
    for (; i < cnt; ++i) {
        ushort4 h = Y4[le[i] + tid]; float c = lc[i];
        a[0].x = fmaf(c, b2f(h.x), a[0].x); a[0].y = fmaf(c, b2f(h.y), a[0].y);
        a[0].z = fmaf(c, b2f(h.z), a[0].z); a[0].w = fmaf(c, b2f(h.w), a[0].w);
    }
#pragma unroll
    for (int u = 4; u > 0; u >>= 1)
#pragma unroll
        for (int q = 0; q < u; ++q) {
            a[q].x += a[q + u].x; a[q].y += a[q + u].y;
            a[q].z += a[q + u].z; a[q].w += a[q + u].w;
        }
    float dv = tc > 0 ? rsqrtf((float)tc) : 0.f;
    // residual + relu
    float4 xr = ((const float4*)Xh)[v * (DH / 4) + tid];
    float x0 = xr.x + fmaxf(dv * a[0].x, 0.f);
    float x1 = xr.y + fmaxf(dv * a[0].y, 0.f);
    float x2 = xr.z + fmaxf(dv * a[0].z, 0.f);
    float x3 = xr.w + fmaxf(dv * a[0].w, 0.f);
    // LayerNorm across the row (64 lanes x 4 elems)
    float s = (x0 + x1) + (x2 + x3);
    float q = fmaf(x0, x0, fmaf(x1, x1, fmaf(x2, x2, x3 * x3)));
#pragma unroll
    for (int o = 1; o < 64; o <<= 1) {
        s += __shfl_xor(s, o, 64);
        q += __shfl_xor(q, o, 64);
    }
    float m = s * (1.0f / DH);
    float var = q * (1.0f / DH) - m * m;
    float rstd = rsqrtf(var + 1e-5f);
    float4 g4 = ((const float4*)g)[tid];
    float4 b4 = ((const float4*)b)[tid];
    float4 o;
    o.x = (x0 - m) * rstd * g4.x + b4.x;
    o.y = (x1 - m) * rstd * g4.y + b4.y;
    o.z = (x2 - m) * rstd * g4.z + b4.z;
    o.w = (x3 - m) * rstd * g4.w + b4.w;
    ((float4*)Xh)[v * (DH / 4) + tid] = o;
    ushort4 ob = {f2bf(o.x), f2bf(o.y), f2bf(o.z), f2bf(o.w)};
    ((ushort4*)Xhb)[v * (DH / 4) + tid] = ob;
}

// ------- fused mean-pool + classifier + softmax (64 thr, bf16 src) -------
__global__ __launch_bounds__(64) void pool_classify(const unsigned short* __restrict__ Xhb,
                                                    const int* __restrict__ edge_cnt,
                                                    const int* __restrict__ edge_list,
                                                    const float* __restrict__ Wc,
                                                    const float* __restrict__ bc,
                                                    float* __restrict__ out) {
    int e = blockIdx.x;
    int tid = threadIdx.x;
    __shared__ int lv[CAP_E];
    int tc = edge_cnt[e << 4];
    int cnt = min(tc, CAP_E);
    for (int j = tid; j < cnt; j += 64) lv[j] = edge_list[e * CAP_E + j] * (DH / 4);
    __syncthreads();
    const ushort4* X4 = (const ushort4*)Xhb;
    float4 a[8];
#pragma unroll
    for (int u = 0; u < 8; ++u) a[u] = (float4){0, 0, 0, 0};
    int i = 0;
    for (; i + 8 <= cnt; i += 8) {
#pragma unroll
        for (int u = 0; u < 8; ++u) {
            ushort4 h = X4[lv[i + u] + tid];
            a[u].x += b2f(h.x); a[u].y += b2f(h.y);
            a[u].z += b2f(h.z); a[u].w += b2f(h.w);
        }
    }
    for (; i < cnt; ++i) {
        ushort4 h = X4[lv[i] + tid];
        a[0].x += b2f(h.x); a[0].y += b2f(h.y);
        a[0].z += b2f(h.z); a[0].w += b2f(h.w);
    }
#pragma unroll
    for (int u = 4; u > 0; u >>= 1)
#pragma unroll
        for (int q = 0; q < u; ++q) {
            a[q].x += a[q + u].x; a[q].y += a[q + u].y;
            a[q].z += a[q + u].z; a[q].w += a[q + u].w;
        }
    float inv = tc > 0 ? 1.0f / (float)tc : 1.0f;
    float4 val = {a[0].x * inv, a[0].y * inv, a[0].z * inv, a[0].w * inv};
    const float4* W4 = (const float4*)Wc;
    float4 w0 = W4[tid], w1 = W4[64 + tid];
    float p0 = val.x * w0.x + val.y * w0.y + val.z * w0.z + val.w * w0.w;
    float p1 = val.x * w1.x + val.y * w1.y + val.z * w1.z + val.w * w1.w;
#pragma unroll
    for (int o = 32; o > 0; o >>= 1) {
        p0 += __shfl_down(p0, o, 64);
        p1 += __shfl_down(p1, o, 64);
    }
    if (tid == 0) {
        float l0 = p0 + bc[0], l1 = p1 + bc[1];
        float mx = fmaxf(l0, l1);
        float e0 = expf(l0 - mx), e1 = expf(l1 - mx);
        float s = 1.0f / (e0 + e1);
        out[e * 2 + 0] = e0 * s;
        out[e * 2 + 1] = e1 * s;
    }
}

extern "C" void kernel_launch(void* const* d_in, const int* in_sizes, int n_in,
                              void* d_out, int out_size, void* d_ws, size_t ws_size,
                              hipStream_t stream) {
    const float* X  = (const float*)d_in[0];
    const float* H  = (const float*)d_in[1];
    const float* Wp = (const float*)d_in[2];
    const float* W0 = (const float*)d_in[3];
    const float* W1 = (const float*)d_in[4];
    const float* g0 = (const float*)d_in[5];
    const float* b0 = (const float*)d_in[6];
    const float* g1 = (const float*)d_in[7];
    const float* b1 = (const float*)d_in[8];
    const float* Wc = (const float*)d_in[9];
    const float* bc = (const float*)d_in[10];
    float* out = (float*)d_out;

    float* ws = (float*)d_ws;
    float* Xh  = ws + OFF_XH;
    unsigned short* Ub  = (unsigned short*)(ws + OFF_UB);
    unsigned short* Yb  = (unsigned short*)(ws + OFF_YB);
    int* node_cnt  = (int*)(ws + OFF_NCNT);
    int* edge_cnt  = (int*)(ws + OFF_ECNT);
    int* edge_list = (int*)(ws + OFF_EL);
    int* node_list = (int*)(ws + OFF_NL);
    unsigned short* Xhb = (unsigned short*)(ws + OFF_XHB);

    // node_cnt and edge_cnt are contiguous: one memset for both
    hipMemsetAsync(node_cnt, 0, (size_t)(NV + NE * 16) * sizeof(int), stream);

    // fused: proj GEMM (blocks 0..255) + H scan (wave-per-half-row)
    scan_proj<<<NPROJ + NSCAN, 256, 0, stream>>>(H, X, Wp, Xh, Xhb,
                                                 edge_cnt, node_cnt, edge_list, node_list);

    const float* Ws[2] = {W0, W1};
    const float* gs[2] = {g0, g1};
    const float* bs[2] = {b0, b1};
    for (int l = 0; l < 2; ++l) {
        gemm_u<<<NV / 32, 256, 0, stream>>>(Xhb, Ws[l], Ub);
        edge_gather<<<NE, 64, 0, stream>>>(Ub, edge_cnt, edge_list, node_cnt, Yb);
        node_ln<<<NV, 64, 0, stream>>>(Yb, node_cnt, node_list, edge_cnt,
                                       Xh, Xhb, gs[l], bs[l]);
    }

    pool_classify<<<NE, 64, 0, stream>>>(Xhb, edge_cnt, edge_list, Wc, bc, out);
}